// Round 2
// baseline (3295.094 us; speedup 1.0000x reference)
//
#include <hip/hip_runtime.h>
#include <hip/hip_bf16.h>

typedef __hip_bfloat16 bf16;

#define B_    4
#define CIN   32
#define HH    256
#define WW    256
#define C1    384
#define NHEADS 4
#define DH    32
#define NPIX  65536
#define CMID  128
#define COUT  32

static __device__ __forceinline__ float u2f(unsigned short u) {
    unsigned int x = ((unsigned int)u) << 16;
    return __uint_as_float(x);
}
static __device__ __forceinline__ unsigned short f2u(float f) {
    bf16 h = __float2bfloat16(f);
    return __builtin_bit_cast(unsigned short, h);
}

__global__ __launch_bounds__(256) void k_zero(float* __restrict__ p, int n) {
    int i = blockIdx.x * 256 + threadIdx.x;
    if (i < n) p[i] = 0.f;
}

// ---------------- conv1: x(4,32,256,256) * w1(384,32,3,3) + b1 -> qkv bf16 ----------------
// grid: (C1/8, HH, nb); qkv indexed by LOCAL batch bl, x by true batch b0+bl
__global__ __launch_bounds__(256) void k_conv1(
    const float* __restrict__ x, const float* __restrict__ w1,
    const float* __restrict__ b1, bf16* __restrict__ qkv, int b0)
{
    const int co0 = blockIdx.x * 8;
    const int y   = blockIdx.y;
    const int bl  = blockIdx.z;
    const int b   = b0 + bl;
    const int tx  = threadIdx.x;

    __shared__ float xs[4][3][264];
    float acc[8];
#pragma unroll
    for (int i = 0; i < 8; i++) acc[i] = 0.f;

    for (int cit = 0; cit < CIN; cit += 4) {
        __syncthreads();
        for (int i = tx; i < 4 * 774; i += 256) {
            int ci = i / 774;
            int r  = i % 774;
            int dy = r / 258;
            int xx = r % 258 - 1;
            int yy = y + dy - 1;
            float v = 0.f;
            if (xx >= 0 && xx < WW && yy >= 0 && yy < HH)
                v = x[(((size_t)b * CIN + cit + ci) * HH + yy) * WW + xx];
            xs[ci][dy][r % 258] = v;
        }
        __syncthreads();
#pragma unroll
        for (int ci = 0; ci < 4; ci++) {
            float xv[9];
#pragma unroll
            for (int dy = 0; dy < 3; dy++)
#pragma unroll
                for (int dx = 0; dx < 3; dx++)
                    xv[dy * 3 + dx] = xs[ci][dy][tx + dx];
#pragma unroll
            for (int co = 0; co < 8; co++) {
                const float* wp = w1 + ((size_t)(co0 + co) * CIN + cit + ci) * 9;
                float s = acc[co];
#pragma unroll
                for (int k = 0; k < 9; k++) s += wp[k] * xv[k];
                acc[co] = s;
            }
        }
    }
#pragma unroll
    for (int co = 0; co < 8; co++) {
        float v = acc[co] + b1[co0 + co];
        qkv[(size_t)(bl * C1 + co0 + co) * NPIX + y * WW + tx] = __float2bfloat16(v);
    }
}

// ---------------- softmax stats over k rows: max and 1/sum(exp) ----------------
// grid: (nb*128)
__global__ __launch_bounds__(256) void k_stats(
    const bf16* __restrict__ qkv, float* __restrict__ rmax, float* __restrict__ rinv, int b0)
{
    const int bl = blockIdx.x >> 7;
    const int r  = blockIdx.x & 127;
    const int row = (b0 + bl) * CMID + r;
    const ushort4* kp = (const ushort4*)((const unsigned short*)qkv +
                        (size_t)(bl * C1 + 128 + r) * NPIX);
    __shared__ float red[256];
    const int tx = threadIdx.x;

    float m = -3.4e38f;
    for (int i = tx; i < NPIX / 4; i += 256) {
        ushort4 u = kp[i];
        m = fmaxf(m, fmaxf(fmaxf(u2f(u.x), u2f(u.y)), fmaxf(u2f(u.z), u2f(u.w))));
    }
    red[tx] = m;
    __syncthreads();
    for (int s = 128; s > 0; s >>= 1) {
        if (tx < s) red[tx] = fmaxf(red[tx], red[tx + s]);
        __syncthreads();
    }
    m = red[0];
    __syncthreads();

    float sum = 0.f;
    for (int i = tx; i < NPIX / 4; i += 256) {
        ushort4 u = kp[i];
        sum += __expf(u2f(u.x) - m) + __expf(u2f(u.y) - m) +
               __expf(u2f(u.z) - m) + __expf(u2f(u.w) - m);
    }
    red[tx] = sum;
    __syncthreads();
    for (int s = 128; s > 0; s >>= 1) {
        if (tx < s) red[tx] += red[tx + s];
        __syncthreads();
    }
    if (tx == 0) { rmax[row] = m; rinv[row] = 1.f / red[0]; }
}

// ---------------- in-place: k -> softmax(k) (bf16) ----------------
__global__ __launch_bounds__(256) void k_ptrans(
    bf16* __restrict__ qkv, const float* __restrict__ rmax, const float* __restrict__ rinv,
    int b0, int nb)
{
    size_t g = (size_t)blockIdx.x * 256 + threadIdx.x;   // ushort4 groups
    if (g >= (size_t)nb * CMID * NPIX / 4) return;
    size_t E = g * 4;
    int rl = (int)(E >> 16);           // bl*128 + r
    int bl = rl >> 7;
    int r  = rl & 127;
    int n  = (int)(E & 65535);
    int row = (b0 + bl) * CMID + r;
    unsigned short* p = (unsigned short*)qkv + (size_t)(bl * C1 + 128 + r) * NPIX + n;
    float m = rmax[row], z = rinv[row];
    ushort4 u = *(ushort4*)p;
    u.x = f2u(__expf(u2f(u.x) - m) * z);
    u.y = f2u(__expf(u2f(u.y) - m) * z);
    u.z = f2u(__expf(u2f(u.z) - m) * z);
    u.w = f2u(__expf(u2f(u.w) - m) * z);
    *(ushort4*)p = u;
}

// ---------------- weights[bh,d,e] = sum_n q[d,n] * p[e,n]  (atomic accumulate) ----------------
// grid: (NPIX/1024, nb*4)
__global__ __launch_bounds__(256) void k_weights(
    const bf16* __restrict__ qkv, float* __restrict__ wts, int b0)
{
    const int bl = blockIdx.y >> 2, h = blockIdx.y & 3;
    const int bh = (b0 + bl) * NHEADS + h;
    const int wv = threadIdx.x >> 6, lane = threadIdx.x & 63;
    const int n0 = blockIdx.x * 1024 + wv * 256;
    const int d0 = (lane >> 3) * 4, e0 = (lane & 7) * 4;
    const unsigned short* qb = (const unsigned short*)qkv;

    size_t qch[4], pch[4];
#pragma unroll
    for (int i = 0; i < 4; i++) {
        qch[i] = (size_t)(bl * C1 + h * DH + d0 + i) * NPIX;
        pch[i] = (size_t)(bl * C1 + 128 + h * DH + e0 + i) * NPIX;
    }

    float acc[4][4];
#pragma unroll
    for (int i = 0; i < 4; i++)
#pragma unroll
        for (int j = 0; j < 4; j++) acc[i][j] = 0.f;

    for (int nn = 0; nn < 256; nn += 4) {
        int n = n0 + nn;
        float qf[4][4], pf[4][4];
#pragma unroll
        for (int i = 0; i < 4; i++) {
            ushort4 u = *(const ushort4*)(qb + qch[i] + n);
            qf[i][0] = u2f(u.x); qf[i][1] = u2f(u.y); qf[i][2] = u2f(u.z); qf[i][3] = u2f(u.w);
            ushort4 v = *(const ushort4*)(qb + pch[i] + n);
            pf[i][0] = u2f(v.x); pf[i][1] = u2f(v.y); pf[i][2] = u2f(v.z); pf[i][3] = u2f(v.w);
        }
#pragma unroll
        for (int di = 0; di < 4; di++)
#pragma unroll
            for (int j = 0; j < 4; j++)
#pragma unroll
                for (int ei = 0; ei < 4; ei++)
                    acc[di][ei] += qf[di][j] * pf[ei][j];
    }
    float* wp = wts + (size_t)bh * 1024;
#pragma unroll
    for (int di = 0; di < 4; di++)
#pragma unroll
        for (int ei = 0; ei < 4; ei++)
            atomicAdd(&wp[(d0 + di) * 32 + e0 + ei], acc[di][ei]);
}

// ---------------- aout[e,n] = sum_d W[d,e] * v[d,n] -> WRITES INTO q region of qkv ----------------
// grid: (NPIX/256, nb*4)
__global__ __launch_bounds__(256) void k_attnout(
    bf16* __restrict__ qkv, const float* __restrict__ wts, int b0)
{
    const int bl = blockIdx.y >> 2, h = blockIdx.y & 3;
    const int bh = (b0 + bl) * NHEADS + h;
    const int wv = threadIdx.x >> 6, lane = threadIdx.x & 63;
    const int e0 = wv * 8;
    const int n = blockIdx.x * 256 + lane * 4;

    __shared__ float Ws[32][32];
    for (int i = threadIdx.x; i < 1024; i += 256)
        Ws[i >> 5][i & 31] = wts[(size_t)bh * 1024 + i];
    __syncthreads();

    float acc[8][4];
#pragma unroll
    for (int e = 0; e < 8; e++)
#pragma unroll
        for (int j = 0; j < 4; j++) acc[e][j] = 0.f;

    const unsigned short* vb = (const unsigned short*)qkv;
    for (int d = 0; d < 32; d++) {
        ushort4 u = *(const ushort4*)(vb + (size_t)(bl * C1 + 256 + h * DH + d) * NPIX + n);
        float v0 = u2f(u.x), v1 = u2f(u.y), v2 = u2f(u.z), v3 = u2f(u.w);
#pragma unroll
        for (int e = 0; e < 8; e++) {
            float w = Ws[d][e0 + e];
            acc[e][0] += w * v0; acc[e][1] += w * v1;
            acc[e][2] += w * v2; acc[e][3] += w * v3;
        }
    }
#pragma unroll
    for (int e = 0; e < 8; e++) {
        ushort4 o;
        o.x = f2u(acc[e][0]); o.y = f2u(acc[e][1]);
        o.z = f2u(acc[e][2]); o.w = f2u(acc[e][3]);
        // write into dead q-channel region: channel h*32+e0+e of local batch bl
        *(ushort4*)((unsigned short*)qkv +
                    (size_t)(bl * C1 + h * DH + e0 + e) * NPIX + n) = o;
    }
}

// ---------------- conv2: reads q-region of qkv (=attn out, 128ch) -> d_out fp32 ----------------
// grid: (COUT/8, HH, nb)
__global__ __launch_bounds__(256) void k_conv2(
    const bf16* __restrict__ qkv, const float* __restrict__ w2,
    const float* __restrict__ b2, float* __restrict__ out, int b0)
{
    const int co0 = blockIdx.x * 8;
    const int y   = blockIdx.y;
    const int bl  = blockIdx.z;
    const int b   = b0 + bl;
    const int tx  = threadIdx.x;

    __shared__ float xs[8][3][264];
    float acc[8];
#pragma unroll
    for (int i = 0; i < 8; i++) acc[i] = 0.f;

    const unsigned short* ab = (const unsigned short*)qkv;
    for (int cit = 0; cit < CMID; cit += 8) {
        __syncthreads();
        for (int i = tx; i < 8 * 774; i += 256) {
            int ci = i / 774;
            int r  = i % 774;
            int dy = r / 258;
            int xx = r % 258 - 1;
            int yy = y + dy - 1;
            float v = 0.f;
            if (xx >= 0 && xx < WW && yy >= 0 && yy < HH)
                v = u2f(ab[(size_t)(bl * C1 + cit + ci) * NPIX + yy * WW + xx]);
            xs[ci][dy][r % 258] = v;
        }
        __syncthreads();
#pragma unroll
        for (int ci = 0; ci < 8; ci++) {
            float xv[9];
#pragma unroll
            for (int dy = 0; dy < 3; dy++)
#pragma unroll
                for (int dx = 0; dx < 3; dx++)
                    xv[dy * 3 + dx] = xs[ci][dy][tx + dx];
#pragma unroll
            for (int co = 0; co < 8; co++) {
                const float* wp = w2 + ((size_t)(co0 + co) * CMID + cit + ci) * 9;
                float s = acc[co];
#pragma unroll
                for (int k = 0; k < 9; k++) s += wp[k] * xv[k];
                acc[co] = s;
            }
        }
    }
#pragma unroll
    for (int co = 0; co < 8; co++)
        out[(size_t)(b * COUT + co0 + co) * NPIX + y * WW + tx] = acc[co] + b2[co0 + co];
}

extern "C" void kernel_launch(void* const* d_in, const int* in_sizes, int n_in,
                              void* d_out, int out_size, void* d_ws, size_t ws_size,
                              hipStream_t stream) {
    const float* x  = (const float*)d_in[0];
    const float* w1 = (const float*)d_in[1];
    const float* b1 = (const float*)d_in[2];
    const float* w2 = (const float*)d_in[3];
    const float* b2 = (const float*)d_in[4];
    float* out = (float*)d_out;

    // workspace layout: small arrays FIRST, then qkv
    char* ws = (char*)d_ws;
    float* rmax = (float*)(ws);            // 512 f  = 2048 B
    float* rinv = (float*)(ws + 2048);     // 512 f  = 2048 B
    float* wts  = (float*)(ws + 4096);     // 16*1024 f = 65536 B
    bf16*  qkv  = (bf16*)(ws + 69632);

    // full path needs 69632 + 4*384*65536*2 = 201,396,224 B (~192.1 MiB)
    // per-batch path needs 69632 + 384*65536*2 = 50,401,280 B (~48.1 MiB)
    const bool full = ws_size >= 201396224ull;
    const int nb = full ? 4 : 1;

    k_zero<<<dim3(64), 256, 0, stream>>>(wts, 16 * 1024);

    for (int b0 = 0; b0 < B_; b0 += nb) {
        k_conv1<<<dim3(C1 / 8, HH, nb), 256, 0, stream>>>(x, w1, b1, qkv, b0);
        k_stats<<<dim3(nb * CMID), 256, 0, stream>>>(qkv, rmax, rinv, b0);
        k_ptrans<<<dim3((nb * CMID * NPIX / 4 + 255) / 256), 256, 0, stream>>>(qkv, rmax, rinv, b0, nb);
        k_weights<<<dim3(NPIX / 1024, nb * NHEADS), 256, 0, stream>>>(qkv, wts, b0);
        k_attnout<<<dim3(NPIX / 256, nb * NHEADS), 256, 0, stream>>>(qkv, wts, b0);
        k_conv2<<<dim3(COUT / 8, HH, nb), 256, 0, stream>>>(qkv, w2, b2, out, b0);
    }
}

// Round 3
// 1812.868 us; speedup vs baseline: 1.8176x; 1.8176x over previous
//
#include <hip/hip_runtime.h>
#include <hip/hip_bf16.h>

typedef __hip_bfloat16 bf16;
typedef __attribute__((ext_vector_type(8))) short short8;
typedef __attribute__((ext_vector_type(4))) float f32x4;

#define B_    4
#define CIN   32
#define HH    256
#define WW    256
#define C1    384
#define NHEADS 4
#define DH    32
#define NPIX  65536
#define CMID  128
#define COUT  32

static __device__ __forceinline__ float u2f(unsigned short u) {
    unsigned int x = ((unsigned int)u) << 16;
    return __uint_as_float(x);
}
static __device__ __forceinline__ unsigned short f2u(float f) {
    bf16 h = __float2bfloat16(f);
    return __builtin_bit_cast(unsigned short, h);
}

__global__ __launch_bounds__(256) void k_zero(float* __restrict__ p, int n) {
    int i = blockIdx.x * 256 + threadIdx.x;
    if (i < n) p[i] = 0.f;
}

// ---------------- conv1 via MFMA implicit GEMM ----------------
// grid: (C1/64, HH, nb). Block: 64 co x 256 px (one row, 2 chunks of 128).
// 4 waves; each wave: 4 co-tiles (A, registers) x 2 n-tiles, 9 taps, K=32=CIN.
__global__ __launch_bounds__(256, 2) void k_conv1_mfma(
    const float* __restrict__ x, const float* __restrict__ w1,
    const float* __restrict__ b1, bf16* __restrict__ qkv, int b0)
{
    const int co0 = blockIdx.x * 64;
    const int y   = blockIdx.y;
    const int bl  = blockIdx.z;
    const int b   = b0 + bl;
    const int tx  = threadIdx.x;
    const int wv  = tx >> 6;
    const int l   = tx & 63;
    const int lhi = l >> 4;     // 0..3 (ci-group)
    const int llo = l & 15;

    __shared__ short ws_w[9][4][64][8];   // [tap][ci_hi][co_local][ci_lo]  36864 B
    __shared__ short xs[3][4][136][8];    // [row][ci_hi][col][ci_lo]       26112 B

    // ---- stage weights once: thread t -> co_local=t>>2, ci_hi=t&3 ----
    {
        const int co_l = tx >> 2;
        const int ch   = tx & 3;
        const float* wp = w1 + ((size_t)(co0 + co_l) * CIN + ch * 8) * 9;
        float wb[72];
#pragma unroll
        for (int i = 0; i < 18; i++) {
            float4 v = ((const float4*)wp)[i];
            wb[i*4+0] = v.x; wb[i*4+1] = v.y; wb[i*4+2] = v.z; wb[i*4+3] = v.w;
        }
#pragma unroll
        for (int tap = 0; tap < 9; tap++) {
            short8 h;
#pragma unroll
            for (int c = 0; c < 8; c++) h[c] = (short)f2u(wb[c*9 + tap]);
            *(short8*)&ws_w[tap][ch][co_l][0] = h;
        }
    }
    __syncthreads();

    // ---- A fragments (weights) into registers: afr[tap][mc] ----
    short8 afr[9][4];
#pragma unroll
    for (int tap = 0; tap < 9; tap++)
#pragma unroll
        for (int mc = 0; mc < 4; mc++)
            afr[tap][mc] = *(const short8*)&ws_w[tap][lhi][mc*16 + llo][0];

    float bias[4][4];
#pragma unroll
    for (int mc = 0; mc < 4; mc++)
#pragma unroll
        for (int r = 0; r < 4; r++)
            bias[mc][r] = b1[co0 + mc*16 + lhi*4 + r];

    for (int chunk = 0; chunk < 2; chunk++) {
        __syncthreads();   // previous chunk's readers done
        const int px0 = chunk * 128;
        // ---- stage x patch: 3 rows x 130 cols x 32 ci, transposed to [ci_hi][col][ci_lo] ----
        for (int r = 0; r < 3; r++) {
            int yy = y + r - 1;
            for (int c = tx; c < 130; c += 256) {
                int xx = px0 + c - 1;
                bool ok = (yy >= 0) && (yy < HH) && (xx >= 0) && (xx < WW);
#pragma unroll
                for (int ch = 0; ch < 4; ch++) {
                    short8 h;
#pragma unroll
                    for (int j = 0; j < 8; j++) {
                        float v = ok ? x[(((size_t)b * CIN + ch*8 + j) * HH + yy) * WW + xx] : 0.f;
                        h[j] = (short)f2u(v);
                    }
                    *(short8*)&xs[r][ch][c][0] = h;
                }
            }
        }
        __syncthreads();

        // ---- compute: 2 n-tiles x 4 co-tiles x 9 taps ----
        f32x4 acc[2][4];
#pragma unroll
        for (int t = 0; t < 2; t++)
#pragma unroll
            for (int mc = 0; mc < 4; mc++) acc[t][mc] = (f32x4){0.f, 0.f, 0.f, 0.f};

#pragma unroll
        for (int dy = 0; dy < 3; dy++)
#pragma unroll
            for (int dx = 0; dx < 3; dx++)
#pragma unroll
                for (int t = 0; t < 2; t++) {
                    short8 bfr = *(const short8*)&xs[dy][lhi][wv*32 + t*16 + llo + dx][0];
#pragma unroll
                    for (int mc = 0; mc < 4; mc++)
                        acc[t][mc] = __builtin_amdgcn_mfma_f32_16x16x32_bf16(
                            afr[dy*3+dx][mc], bfr, acc[t][mc], 0, 0, 0);
                }

        // ---- epilogue: bias + bf16 store (D: col=llo -> pixel, row=lhi*4+r -> co) ----
#pragma unroll
        for (int t = 0; t < 2; t++) {
            int p = y * WW + px0 + wv*32 + t*16 + llo;
#pragma unroll
            for (int mc = 0; mc < 4; mc++)
#pragma unroll
                for (int r = 0; r < 4; r++) {
                    int co = co0 + mc*16 + lhi*4 + r;
                    qkv[(size_t)(bl * C1 + co) * NPIX + p] =
                        __float2bfloat16(acc[t][mc][r] + bias[mc][r]);
                }
        }
    }
}

// ---------------- softmax stats over k rows: max and 1/sum(exp) ----------------
__global__ __launch_bounds__(256) void k_stats(
    const bf16* __restrict__ qkv, float* __restrict__ rmax, float* __restrict__ rinv, int b0)
{
    const int bl = blockIdx.x >> 7;
    const int r  = blockIdx.x & 127;
    const int row = (b0 + bl) * CMID + r;
    const ushort4* kp = (const ushort4*)((const unsigned short*)qkv +
                        (size_t)(bl * C1 + 128 + r) * NPIX);
    __shared__ float red[256];
    const int tx = threadIdx.x;

    float m = -3.4e38f;
    for (int i = tx; i < NPIX / 4; i += 256) {
        ushort4 u = kp[i];
        m = fmaxf(m, fmaxf(fmaxf(u2f(u.x), u2f(u.y)), fmaxf(u2f(u.z), u2f(u.w))));
    }
    red[tx] = m;
    __syncthreads();
    for (int s = 128; s > 0; s >>= 1) {
        if (tx < s) red[tx] = fmaxf(red[tx], red[tx + s]);
        __syncthreads();
    }
    m = red[0];
    __syncthreads();

    float sum = 0.f;
    for (int i = tx; i < NPIX / 4; i += 256) {
        ushort4 u = kp[i];
        sum += __expf(u2f(u.x) - m) + __expf(u2f(u.y) - m) +
               __expf(u2f(u.z) - m) + __expf(u2f(u.w) - m);
    }
    red[tx] = sum;
    __syncthreads();
    for (int s = 128; s > 0; s >>= 1) {
        if (tx < s) red[tx] += red[tx + s];
        __syncthreads();
    }
    if (tx == 0) { rmax[row] = m; rinv[row] = 1.f / red[0]; }
}

// ---------------- in-place: k -> softmax(k) (bf16) ----------------
__global__ __launch_bounds__(256) void k_ptrans(
    bf16* __restrict__ qkv, const float* __restrict__ rmax, const float* __restrict__ rinv,
    int b0, int nb)
{
    size_t g = (size_t)blockIdx.x * 256 + threadIdx.x;
    if (g >= (size_t)nb * CMID * NPIX / 4) return;
    size_t E = g * 4;
    int rl = (int)(E >> 16);
    int bl = rl >> 7;
    int r  = rl & 127;
    int n  = (int)(E & 65535);
    int row = (b0 + bl) * CMID + r;
    unsigned short* p = (unsigned short*)qkv + (size_t)(bl * C1 + 128 + r) * NPIX + n;
    float m = rmax[row], z = rinv[row];
    ushort4 u = *(ushort4*)p;
    u.x = f2u(__expf(u2f(u.x) - m) * z);
    u.y = f2u(__expf(u2f(u.y) - m) * z);
    u.z = f2u(__expf(u2f(u.z) - m) * z);
    u.w = f2u(__expf(u2f(u.w) - m) * z);
    *(ushort4*)p = u;
}

// ---------------- weights[bh,d,e] = sum_n q[d,n] * p[e,n] ----------------
__global__ __launch_bounds__(256) void k_weights(
    const bf16* __restrict__ qkv, float* __restrict__ wts, int b0)
{
    const int bl = blockIdx.y >> 2, h = blockIdx.y & 3;
    const int bh = (b0 + bl) * NHEADS + h;
    const int wv = threadIdx.x >> 6, lane = threadIdx.x & 63;
    const int n0 = blockIdx.x * 1024 + wv * 256;
    const int d0 = (lane >> 3) * 4, e0 = (lane & 7) * 4;
    const unsigned short* qb = (const unsigned short*)qkv;

    size_t qch[4], pch[4];
#pragma unroll
    for (int i = 0; i < 4; i++) {
        qch[i] = (size_t)(bl * C1 + h * DH + d0 + i) * NPIX;
        pch[i] = (size_t)(bl * C1 + 128 + h * DH + e0 + i) * NPIX;
    }

    float acc[4][4];
#pragma unroll
    for (int i = 0; i < 4; i++)
#pragma unroll
        for (int j = 0; j < 4; j++) acc[i][j] = 0.f;

    for (int nn = 0; nn < 256; nn += 4) {
        int n = n0 + nn;
        float qf[4][4], pf[4][4];
#pragma unroll
        for (int i = 0; i < 4; i++) {
            ushort4 u = *(const ushort4*)(qb + qch[i] + n);
            qf[i][0] = u2f(u.x); qf[i][1] = u2f(u.y); qf[i][2] = u2f(u.z); qf[i][3] = u2f(u.w);
            ushort4 v = *(const ushort4*)(qb + pch[i] + n);
            pf[i][0] = u2f(v.x); pf[i][1] = u2f(v.y); pf[i][2] = u2f(v.z); pf[i][3] = u2f(v.w);
        }
#pragma unroll
        for (int di = 0; di < 4; di++)
#pragma unroll
            for (int j = 0; j < 4; j++)
#pragma unroll
                for (int ei = 0; ei < 4; ei++)
                    acc[di][ei] += qf[di][j] * pf[ei][j];
    }
    float* wp = wts + (size_t)bh * 1024;
#pragma unroll
    for (int di = 0; di < 4; di++)
#pragma unroll
        for (int ei = 0; ei < 4; ei++)
            atomicAdd(&wp[(d0 + di) * 32 + e0 + ei], acc[di][ei]);
}

// ---------------- aout[e,n] = sum_d W[d,e]*v[d,n] -> into q region of qkv ----------------
__global__ __launch_bounds__(256) void k_attnout(
    bf16* __restrict__ qkv, const float* __restrict__ wts, int b0)
{
    const int bl = blockIdx.y >> 2, h = blockIdx.y & 3;
    const int bh = (b0 + bl) * NHEADS + h;
    const int wv = threadIdx.x >> 6, lane = threadIdx.x & 63;
    const int e0 = wv * 8;
    const int n = blockIdx.x * 256 + lane * 4;

    __shared__ float Ws[32][32];
    for (int i = threadIdx.x; i < 1024; i += 256)
        Ws[i >> 5][i & 31] = wts[(size_t)bh * 1024 + i];
    __syncthreads();

    float acc[8][4];
#pragma unroll
    for (int e = 0; e < 8; e++)
#pragma unroll
        for (int j = 0; j < 4; j++) acc[e][j] = 0.f;

    const unsigned short* vb = (const unsigned short*)qkv;
    for (int d = 0; d < 32; d++) {
        ushort4 u = *(const ushort4*)(vb + (size_t)(bl * C1 + 256 + h * DH + d) * NPIX + n);
        float v0 = u2f(u.x), v1 = u2f(u.y), v2 = u2f(u.z), v3 = u2f(u.w);
#pragma unroll
        for (int e = 0; e < 8; e++) {
            float w = Ws[d][e0 + e];
            acc[e][0] += w * v0; acc[e][1] += w * v1;
            acc[e][2] += w * v2; acc[e][3] += w * v3;
        }
    }
#pragma unroll
    for (int e = 0; e < 8; e++) {
        ushort4 o;
        o.x = f2u(acc[e][0]); o.y = f2u(acc[e][1]);
        o.z = f2u(acc[e][2]); o.w = f2u(acc[e][3]);
        *(ushort4*)((unsigned short*)qkv +
                    (size_t)(bl * C1 + h * DH + e0 + e) * NPIX + n) = o;
    }
}

// ---------------- conv2 (scalar, div/mod-free staging) ----------------
__global__ __launch_bounds__(256) void k_conv2(
    const bf16* __restrict__ qkv, const float* __restrict__ w2,
    const float* __restrict__ b2, float* __restrict__ out, int b0)
{
    const int co0 = blockIdx.x * 8;
    const int y   = blockIdx.y;
    const int bl  = blockIdx.z;
    const int b   = b0 + bl;
    const int tx  = threadIdx.x;

    __shared__ float xs[8][3][264];
    float acc[8];
#pragma unroll
    for (int i = 0; i < 8; i++) acc[i] = 0.f;

    const unsigned short* ab = (const unsigned short*)qkv;
    for (int cit = 0; cit < CMID; cit += 8) {
        __syncthreads();
#pragma unroll
        for (int ci = 0; ci < 8; ci++)
#pragma unroll
            for (int dy = 0; dy < 3; dy++)
                for (int rep = 0; rep < 2; rep++) {
                    int col = tx + rep * 256;
                    if (col < 258) {
                        int xx = col - 1;
                        int yy = y + dy - 1;
                        float v = 0.f;
                        if (xx >= 0 && xx < WW && yy >= 0 && yy < HH)
                            v = u2f(ab[(size_t)(bl * C1 + cit + ci) * NPIX + yy * WW + xx]);
                        xs[ci][dy][col] = v;
                    }
                }
        __syncthreads();
#pragma unroll
        for (int ci = 0; ci < 8; ci++) {
            float xv[9];
#pragma unroll
            for (int dy = 0; dy < 3; dy++)
#pragma unroll
                for (int dx = 0; dx < 3; dx++)
                    xv[dy * 3 + dx] = xs[ci][dy][tx + dx];
#pragma unroll
            for (int co = 0; co < 8; co++) {
                const float* wp = w2 + ((size_t)(co0 + co) * CMID + cit + ci) * 9;
                float s = acc[co];
#pragma unroll
                for (int k = 0; k < 9; k++) s += wp[k] * xv[k];
                acc[co] = s;
            }
        }
    }
#pragma unroll
    for (int co = 0; co < 8; co++)
        out[(size_t)(b * COUT + co0 + co) * NPIX + y * WW + tx] = acc[co] + b2[co0 + co];
}

extern "C" void kernel_launch(void* const* d_in, const int* in_sizes, int n_in,
                              void* d_out, int out_size, void* d_ws, size_t ws_size,
                              hipStream_t stream) {
    const float* x  = (const float*)d_in[0];
    const float* w1 = (const float*)d_in[1];
    const float* b1 = (const float*)d_in[2];
    const float* w2 = (const float*)d_in[3];
    const float* b2 = (const float*)d_in[4];
    float* out = (float*)d_out;

    char* ws = (char*)d_ws;
    float* rmax = (float*)(ws);
    float* rinv = (float*)(ws + 2048);
    float* wts  = (float*)(ws + 4096);
    bf16*  qkv  = (bf16*)(ws + 69632);

    const bool full = ws_size >= 201396224ull;
    const int nb = full ? 4 : 1;

    k_zero<<<dim3(64), 256, 0, stream>>>(wts, 16 * 1024);

    for (int b0 = 0; b0 < B_; b0 += nb) {
        k_conv1_mfma<<<dim3(C1 / 64, HH, nb), 256, 0, stream>>>(x, w1, b1, qkv, b0);
        k_stats<<<dim3(nb * CMID), 256, 0, stream>>>(qkv, rmax, rinv, b0);
        k_ptrans<<<dim3((nb * CMID * NPIX / 4 + 255) / 256), 256, 0, stream>>>(qkv, rmax, rinv, b0, nb);
        k_weights<<<dim3(NPIX / 1024, nb * NHEADS), 256, 0, stream>>>(qkv, wts, b0);
        k_attnout<<<dim3(NPIX / 256, nb * NHEADS), 256, 0, stream>>>(qkv, wts, b0);
        k_conv2<<<dim3(COUT / 8, HH, nb), 256, 0, stream>>>(qkv, w2, b2, out, b0);
    }
}

// Round 4
// 987.155 us; speedup vs baseline: 3.3380x; 1.8365x over previous
//
#include <hip/hip_runtime.h>
#include <hip/hip_bf16.h>

typedef __hip_bfloat16 bf16;
typedef __attribute__((ext_vector_type(8))) short short8;
typedef __attribute__((ext_vector_type(4))) float f32x4;

#define B_    4
#define CIN   32
#define HH    256
#define WW    256
#define C1    384
#define NHEADS 4
#define DH    32
#define NPIX  65536
#define CMID  128
#define COUT  32

static __device__ __forceinline__ float u2f(unsigned short u) {
    unsigned int x = ((unsigned int)u) << 16;
    return __uint_as_float(x);
}
static __device__ __forceinline__ unsigned short f2u(float f) {
    bf16 h = __float2bfloat16(f);
    return __builtin_bit_cast(unsigned short, h);
}

__global__ __launch_bounds__(256) void k_zero(float* __restrict__ p, int n) {
    int i = blockIdx.x * 256 + threadIdx.x;
    if (i < n) p[i] = 0.f;
}

// ---------------- conv1 via MFMA implicit GEMM ----------------
__global__ __launch_bounds__(256, 2) void k_conv1_mfma(
    const float* __restrict__ x, const float* __restrict__ w1,
    const float* __restrict__ b1, bf16* __restrict__ qkv, int b0)
{
    const int co0 = blockIdx.x * 64;
    const int y   = blockIdx.y;
    const int bl  = blockIdx.z;
    const int b   = b0 + bl;
    const int tx  = threadIdx.x;
    const int wv  = tx >> 6;
    const int l   = tx & 63;
    const int lhi = l >> 4;
    const int llo = l & 15;

    __shared__ short ws_w[9][4][64][8];   // [tap][ci_hi][co_local][ci_lo]  36864 B
    __shared__ short xs[3][4][136][8];    // [row][ci_hi][col][ci_lo]       26112 B

    {
        const int co_l = tx >> 2;
        const int ch   = tx & 3;
        const float* wp = w1 + ((size_t)(co0 + co_l) * CIN + ch * 8) * 9;
        float wb[72];
#pragma unroll
        for (int i = 0; i < 18; i++) {
            float4 v = ((const float4*)wp)[i];
            wb[i*4+0] = v.x; wb[i*4+1] = v.y; wb[i*4+2] = v.z; wb[i*4+3] = v.w;
        }
#pragma unroll
        for (int tap = 0; tap < 9; tap++) {
            short8 h;
#pragma unroll
            for (int c = 0; c < 8; c++) h[c] = (short)f2u(wb[c*9 + tap]);
            *(short8*)&ws_w[tap][ch][co_l][0] = h;
        }
    }
    __syncthreads();

    short8 afr[9][4];
#pragma unroll
    for (int tap = 0; tap < 9; tap++)
#pragma unroll
        for (int mc = 0; mc < 4; mc++)
            afr[tap][mc] = *(const short8*)&ws_w[tap][lhi][mc*16 + llo][0];

    float bias[4][4];
#pragma unroll
    for (int mc = 0; mc < 4; mc++)
#pragma unroll
        for (int r = 0; r < 4; r++)
            bias[mc][r] = b1[co0 + mc*16 + lhi*4 + r];

    for (int chunk = 0; chunk < 2; chunk++) {
        __syncthreads();
        const int px0 = chunk * 128;
        for (int r = 0; r < 3; r++) {
            int yy = y + r - 1;
            for (int c = tx; c < 130; c += 256) {
                int xx = px0 + c - 1;
                bool ok = (yy >= 0) && (yy < HH) && (xx >= 0) && (xx < WW);
#pragma unroll
                for (int ch = 0; ch < 4; ch++) {
                    short8 h;
#pragma unroll
                    for (int j = 0; j < 8; j++) {
                        float v = ok ? x[(((size_t)b * CIN + ch*8 + j) * HH + yy) * WW + xx] : 0.f;
                        h[j] = (short)f2u(v);
                    }
                    *(short8*)&xs[r][ch][c][0] = h;
                }
            }
        }
        __syncthreads();

        f32x4 acc[2][4];
#pragma unroll
        for (int t = 0; t < 2; t++)
#pragma unroll
            for (int mc = 0; mc < 4; mc++) acc[t][mc] = (f32x4){0.f, 0.f, 0.f, 0.f};

#pragma unroll
        for (int dy = 0; dy < 3; dy++)
#pragma unroll
            for (int dx = 0; dx < 3; dx++)
#pragma unroll
                for (int t = 0; t < 2; t++) {
                    short8 bfr = *(const short8*)&xs[dy][lhi][wv*32 + t*16 + llo + dx][0];
#pragma unroll
                    for (int mc = 0; mc < 4; mc++)
                        acc[t][mc] = __builtin_amdgcn_mfma_f32_16x16x32_bf16(
                            afr[dy*3+dx][mc], bfr, acc[t][mc], 0, 0, 0);
                }

#pragma unroll
        for (int t = 0; t < 2; t++) {
            int p = y * WW + px0 + wv*32 + t*16 + llo;
#pragma unroll
            for (int mc = 0; mc < 4; mc++)
#pragma unroll
                for (int r = 0; r < 4; r++) {
                    int co = co0 + mc*16 + lhi*4 + r;
                    qkv[(size_t)(bl * C1 + co) * NPIX + p] =
                        __float2bfloat16(acc[t][mc][r] + bias[mc][r]);
                }
        }
    }
}

// ---------------- softmax stats over k rows: max and 1/sum(exp) ----------------
__global__ __launch_bounds__(256) void k_stats(
    const bf16* __restrict__ qkv, float* __restrict__ rmax, float* __restrict__ rinv, int b0)
{
    const int bl = blockIdx.x >> 7;
    const int r  = blockIdx.x & 127;
    const int row = (b0 + bl) * CMID + r;
    const ushort4* kp = (const ushort4*)((const unsigned short*)qkv +
                        (size_t)(bl * C1 + 128 + r) * NPIX);
    __shared__ float red[256];
    const int tx = threadIdx.x;

    float m = -3.4e38f;
    for (int i = tx; i < NPIX / 4; i += 256) {
        ushort4 u = kp[i];
        m = fmaxf(m, fmaxf(fmaxf(u2f(u.x), u2f(u.y)), fmaxf(u2f(u.z), u2f(u.w))));
    }
    red[tx] = m;
    __syncthreads();
    for (int s = 128; s > 0; s >>= 1) {
        if (tx < s) red[tx] = fmaxf(red[tx], red[tx + s]);
        __syncthreads();
    }
    m = red[0];
    __syncthreads();

    float sum = 0.f;
    for (int i = tx; i < NPIX / 4; i += 256) {
        ushort4 u = kp[i];
        sum += __expf(u2f(u.x) - m) + __expf(u2f(u.y) - m) +
               __expf(u2f(u.z) - m) + __expf(u2f(u.w) - m);
    }
    red[tx] = sum;
    __syncthreads();
    for (int s = 128; s > 0; s >>= 1) {
        if (tx < s) red[tx] += red[tx + s];
        __syncthreads();
    }
    if (tx == 0) { rmax[row] = m; rinv[row] = 1.f / red[0]; }
}

// ---------------- weights[bh,d,e] = sum_n q[d,n] * exp(k[e,n]-m[e])*z[e] ----------------
// (softmax fused: reads RAW k, applies exp in fp32)
__global__ __launch_bounds__(256) void k_weights(
    const bf16* __restrict__ qkv, const float* __restrict__ rmax,
    const float* __restrict__ rinv, float* __restrict__ wts, int b0)
{
    const int bl = blockIdx.y >> 2, h = blockIdx.y & 3;
    const int bh = (b0 + bl) * NHEADS + h;
    const int wv = threadIdx.x >> 6, lane = threadIdx.x & 63;
    const int n0 = blockIdx.x * 1024 + wv * 256;
    const int d0 = (lane >> 3) * 4, e0 = (lane & 7) * 4;
    const unsigned short* qb = (const unsigned short*)qkv;

    size_t qch[4], kch[4];
    float me[4], ze[4];
#pragma unroll
    for (int i = 0; i < 4; i++) {
        qch[i] = (size_t)(bl * C1 + h * DH + d0 + i) * NPIX;
        kch[i] = (size_t)(bl * C1 + 128 + h * DH + e0 + i) * NPIX;
        me[i]  = rmax[(b0 + bl) * CMID + h * DH + e0 + i];
        ze[i]  = rinv[(b0 + bl) * CMID + h * DH + e0 + i];
    }

    float acc[4][4];
#pragma unroll
    for (int i = 0; i < 4; i++)
#pragma unroll
        for (int j = 0; j < 4; j++) acc[i][j] = 0.f;

    for (int nn = 0; nn < 256; nn += 4) {
        int n = n0 + nn;
        float qf[4][4], pf[4][4];
#pragma unroll
        for (int i = 0; i < 4; i++) {
            ushort4 u = *(const ushort4*)(qb + qch[i] + n);
            qf[i][0] = u2f(u.x); qf[i][1] = u2f(u.y); qf[i][2] = u2f(u.z); qf[i][3] = u2f(u.w);
            ushort4 v = *(const ushort4*)(qb + kch[i] + n);
            pf[i][0] = __expf(u2f(v.x) - me[i]) * ze[i];
            pf[i][1] = __expf(u2f(v.y) - me[i]) * ze[i];
            pf[i][2] = __expf(u2f(v.z) - me[i]) * ze[i];
            pf[i][3] = __expf(u2f(v.w) - me[i]) * ze[i];
        }
#pragma unroll
        for (int di = 0; di < 4; di++)
#pragma unroll
            for (int j = 0; j < 4; j++)
#pragma unroll
                for (int ei = 0; ei < 4; ei++)
                    acc[di][ei] += qf[di][j] * pf[ei][j];
    }
    float* wp = wts + (size_t)bh * 1024;
#pragma unroll
    for (int di = 0; di < 4; di++)
#pragma unroll
        for (int ei = 0; ei < 4; ei++)
            atomicAdd(&wp[(d0 + di) * 32 + e0 + ei], acc[di][ei]);
}

// ---------------- aout[e,n] = sum_d W[d,e]*v[d,n] -> into q region of qkv ----------------
__global__ __launch_bounds__(256) void k_attnout(
    bf16* __restrict__ qkv, const float* __restrict__ wts, int b0)
{
    const int bl = blockIdx.y >> 2, h = blockIdx.y & 3;
    const int bh = (b0 + bl) * NHEADS + h;
    const int wv = threadIdx.x >> 6, lane = threadIdx.x & 63;
    const int e0 = wv * 8;
    const int n = blockIdx.x * 256 + lane * 4;

    __shared__ float Ws[32][32];
    for (int i = threadIdx.x; i < 1024; i += 256)
        Ws[i >> 5][i & 31] = wts[(size_t)bh * 1024 + i];
    __syncthreads();

    float acc[8][4];
#pragma unroll
    for (int e = 0; e < 8; e++)
#pragma unroll
        for (int j = 0; j < 4; j++) acc[e][j] = 0.f;

    const unsigned short* vb = (const unsigned short*)qkv;
    for (int d = 0; d < 32; d++) {
        ushort4 u = *(const ushort4*)(vb + (size_t)(bl * C1 + 256 + h * DH + d) * NPIX + n);
        float v0 = u2f(u.x), v1 = u2f(u.y), v2 = u2f(u.z), v3 = u2f(u.w);
#pragma unroll
        for (int e = 0; e < 8; e++) {
            float w = Ws[d][e0 + e];
            acc[e][0] += w * v0; acc[e][1] += w * v1;
            acc[e][2] += w * v2; acc[e][3] += w * v3;
        }
    }
#pragma unroll
    for (int e = 0; e < 8; e++) {
        ushort4 o;
        o.x = f2u(acc[e][0]); o.y = f2u(acc[e][1]);
        o.z = f2u(acc[e][2]); o.w = f2u(acc[e][3]);
        *(ushort4*)((unsigned short*)qkv +
                    (size_t)(bl * C1 + h * DH + e0 + e) * NPIX + n) = o;
    }
}

// ---------------- conv2 via MFMA implicit GEMM ----------------
// grid: (2, HH, nb). Block: one row, 128-px chunk, all 32 co.
// K-loop: 4 ci-chunks of 32. Per wave: 2 co-tiles x 2 n-tiles, 9 taps.
__global__ __launch_bounds__(256, 2) void k_conv2_mfma(
    const bf16* __restrict__ qkv, const float* __restrict__ w2,
    const float* __restrict__ b2, float* __restrict__ out, int b0)
{
    const int px0 = blockIdx.x * 128;
    const int y   = blockIdx.y;
    const int bl  = blockIdx.z;
    const int b   = b0 + bl;
    const int tx  = threadIdx.x;
    const int wv  = tx >> 6;
    const int l   = tx & 63;
    const int lhi = l >> 4;
    const int llo = l & 15;

    __shared__ short ws_w[9][4][32][8];   // [tap][ci_hi][co][ci_lo]  18432 B
    __shared__ short xs[3][4][136][8];    // [row][ci_hi][col][ci_lo] 26112 B

    const unsigned short* ab = (const unsigned short*)qkv;

    f32x4 acc[2][2];   // [n-tile][co-tile]
#pragma unroll
    for (int t = 0; t < 2; t++)
#pragma unroll
        for (int m = 0; m < 2; m++) acc[t][m] = (f32x4){0.f, 0.f, 0.f, 0.f};

    for (int cc = 0; cc < 4; cc++) {
        __syncthreads();
        // stage weights for this ci-chunk: 128 threads, each one (co, ci-group-of-8)
        if (tx < 128) {
            const int co_l = tx >> 2;
            const int ch   = tx & 3;
            const float* wp = w2 + ((size_t)co_l * CMID + cc * 32 + ch * 8) * 9;
            float wb[72];
#pragma unroll
            for (int i = 0; i < 18; i++) {
                float4 v = ((const float4*)wp)[i];
                wb[i*4+0] = v.x; wb[i*4+1] = v.y; wb[i*4+2] = v.z; wb[i*4+3] = v.w;
            }
#pragma unroll
            for (int tap = 0; tap < 9; tap++) {
                short8 h;
#pragma unroll
                for (int c = 0; c < 8; c++) h[c] = (short)f2u(wb[c*9 + tap]);
                *(short8*)&ws_w[tap][ch][co_l][0] = h;
            }
        }
        // stage x patch for this ci-chunk
        for (int r = 0; r < 3; r++) {
            int yy = y + r - 1;
            for (int c = tx; c < 130; c += 256) {
                int xx = px0 + c - 1;
                bool ok = (yy >= 0) && (yy < HH) && (xx >= 0) && (xx < WW);
#pragma unroll
                for (int ch = 0; ch < 4; ch++) {
                    short8 h;
#pragma unroll
                    for (int j = 0; j < 8; j++) {
                        h[j] = ok ? (short)ab[(size_t)(bl * C1 + cc*32 + ch*8 + j) * NPIX + yy * WW + xx]
                                  : (short)0;
                    }
                    *(short8*)&xs[r][ch][c][0] = h;
                }
            }
        }
        __syncthreads();

        short8 afr[9][2];
#pragma unroll
        for (int tap = 0; tap < 9; tap++)
#pragma unroll
            for (int m = 0; m < 2; m++)
                afr[tap][m] = *(const short8*)&ws_w[tap][lhi][m*16 + llo][0];

#pragma unroll
        for (int dy = 0; dy < 3; dy++)
#pragma unroll
            for (int dx = 0; dx < 3; dx++)
#pragma unroll
                for (int t = 0; t < 2; t++) {
                    short8 bfr = *(const short8*)&xs[dy][lhi][wv*32 + t*16 + llo + dx][0];
#pragma unroll
                    for (int m = 0; m < 2; m++)
                        acc[t][m] = __builtin_amdgcn_mfma_f32_16x16x32_bf16(
                            afr[dy*3+dx][m], bfr, acc[t][m], 0, 0, 0);
                }
    }

    // epilogue: bias + fp32 store
#pragma unroll
    for (int t = 0; t < 2; t++) {
        int p = y * WW + px0 + wv*32 + t*16 + llo;
#pragma unroll
        for (int m = 0; m < 2; m++)
#pragma unroll
            for (int r = 0; r < 4; r++) {
                int co = m*16 + lhi*4 + r;
                out[(size_t)(b * COUT + co) * NPIX + p] = acc[t][m][r] + b2[co];
            }
    }
}

extern "C" void kernel_launch(void* const* d_in, const int* in_sizes, int n_in,
                              void* d_out, int out_size, void* d_ws, size_t ws_size,
                              hipStream_t stream) {
    const float* x  = (const float*)d_in[0];
    const float* w1 = (const float*)d_in[1];
    const float* b1 = (const float*)d_in[2];
    const float* w2 = (const float*)d_in[3];
    const float* b2 = (const float*)d_in[4];
    float* out = (float*)d_out;

    char* ws = (char*)d_ws;
    float* rmax = (float*)(ws);
    float* rinv = (float*)(ws + 2048);
    float* wts  = (float*)(ws + 4096);
    bf16*  qkv  = (bf16*)(ws + 69632);

    const bool full = ws_size >= 201396224ull;
    const int nb = full ? 4 : 1;

    k_zero<<<dim3(64), 256, 0, stream>>>(wts, 16 * 1024);

    for (int b0 = 0; b0 < B_; b0 += nb) {
        k_conv1_mfma<<<dim3(C1 / 64, HH, nb), 256, 0, stream>>>(x, w1, b1, qkv, b0);
        k_stats<<<dim3(nb * CMID), 256, 0, stream>>>(qkv, rmax, rinv, b0);
        k_weights<<<dim3(NPIX / 1024, nb * NHEADS), 256, 0, stream>>>(qkv, rmax, rinv, wts, b0);
        k_attnout<<<dim3(NPIX / 256, nb * NHEADS), 256, 0, stream>>>(qkv, wts, b0);
        k_conv2_mfma<<<dim3(2, HH, nb), 256, 0, stream>>>(qkv, w2, b2, out, b0);
    }
}

// Round 5
// 868.224 us; speedup vs baseline: 3.7952x; 1.1370x over previous
//
#include <hip/hip_runtime.h>
#include <hip/hip_bf16.h>

typedef __hip_bfloat16 bf16;
typedef __attribute__((ext_vector_type(8))) short short8;
typedef __attribute__((ext_vector_type(4))) float f32x4;

#define B_    4
#define CIN   32
#define HH    256
#define WW    256
#define C1    384
#define NPIX  65536
#define CMID  128
#define COUT  32
#define PW    258   // padded spatial width

static __device__ __forceinline__ float u2f(unsigned short u) {
    unsigned int x = ((unsigned int)u) << 16;
    return __uint_as_float(x);
}
static __device__ __forceinline__ unsigned short f2u(float f) {
    bf16 h = __float2bfloat16(f);
    return __builtin_bit_cast(unsigned short, h);
}
static __device__ __forceinline__ unsigned int pk2(float lo, float hi) {
    return (unsigned int)f2u(lo) | ((unsigned int)f2u(hi) << 16);
}
// async global->LDS, 16B per lane; dst is wave-uniform base (HW adds lane*16)
static __device__ __forceinline__ void gload16(const void* src, void* dst) {
    __builtin_amdgcn_global_load_lds(
        (const __attribute__((address_space(1))) void*)src,
        (__attribute__((address_space(3))) void*)dst, 16, 0, 0);
}

__global__ __launch_bounds__(256) void k_zero(float* __restrict__ p, int n) {
    int i = blockIdx.x * 256 + threadIdx.x;
    if (i < n) p[i] = 0.f;
}

// ---- w1(384,32,3,3) fp32 -> w1t[tap][cihi4][co384][8] bf16 ----
__global__ __launch_bounds__(256) void k_w1t(const float* __restrict__ w1, short* __restrict__ w1t) {
    const int tap = blockIdx.x;
    for (int i = threadIdx.x; i < 384 * 32; i += 256) {
        int co = i >> 5, cij = i & 31;
        w1t[((size_t)(tap * 4 + (cij >> 3)) * 384 + co) * 8 + (cij & 7)] =
            (short)f2u(w1[(size_t)i * 9 + tap]);
    }
}
// ---- w2(32,128,3,3) fp32 -> w2t[tap][cihi16][co32][8] bf16 ----
__global__ __launch_bounds__(256) void k_w2t(const float* __restrict__ w2, short* __restrict__ w2t) {
    const int tap = blockIdx.x;
    for (int i = threadIdx.x; i < 32 * 128; i += 256) {
        int co = i >> 7, cij = i & 127;
        w2t[((size_t)(tap * 16 + (cij >> 3)) * 32 + co) * 8 + (cij & 7)] =
            (short)f2u(w2[(size_t)i * 9 + tap]);
    }
}

// ---- x(b,32,256,256) fp32 -> xt[bl][row][col][32] bf16, zero-padded borders ----
// grid (258, nb)
__global__ __launch_bounds__(256) void k_xt(const float* __restrict__ x,
                                            unsigned short* __restrict__ xt, int b0) {
    const int row = blockIdx.x, bl = blockIdx.y, b = b0 + bl;
    const int tx = threadIdx.x;
    unsigned int* rp = (unsigned int*)(xt + ((size_t)(bl * PW + row) * PW) * 32);
    if (row == 0 || row == PW - 1) {
        for (int i = tx; i < PW * 16; i += 256) rp[i] = 0u;   // 258 cols * 64B
        return;
    }
    if (tx < 2) {  // border cols 0 and 257
        unsigned int* cp = rp + (size_t)(tx * (PW - 1)) * 16;
#pragma unroll
        for (int i = 0; i < 16; i++) cp[i] = 0u;
    }
    const int col = tx + 1;
    const size_t px = (size_t)(row - 1) * WW + tx;
    unsigned int pk[16];
#pragma unroll
    for (int c2 = 0; c2 < 16; c2++) {
        float v0 = x[((size_t)b * CIN + 2 * c2) * NPIX + px];
        float v1 = x[((size_t)b * CIN + 2 * c2 + 1) * NPIX + px];
        pk[c2] = pk2(v0, v1);
    }
    uint4* dst = (uint4*)(rp + (size_t)col * 16);
#pragma unroll
    for (int q = 0; q < 4; q++)
        dst[q] = make_uint4(pk[q * 4], pk[q * 4 + 1], pk[q * 4 + 2], pk[q * 4 + 3]);
}

// ---- conv1: implicit GEMM, A from w1t (global L2), B staged via global_load_lds ----
// grid (6, 256, nb); block 64co x 256px (2 chunks of 128)
__global__ __launch_bounds__(256, 4) void k_conv1(
    const unsigned short* __restrict__ xt, const short* __restrict__ w1t,
    const float* __restrict__ b1, unsigned short* __restrict__ qkv, int nb)
{
    const int co0 = blockIdx.x * 64;
    const int y   = blockIdx.y;
    const int bl  = blockIdx.z;
    const int tx  = threadIdx.x;
    const int wv  = tx >> 6, l = tx & 63;
    const int lhi = l >> 4, llo = l & 15;

    __shared__ short xs[3 * 132 * 32];   // [row][col][ci] 25344 B

    float bias[4][4];
#pragma unroll
    for (int mc = 0; mc < 4; mc++)
#pragma unroll
        for (int r = 0; r < 4; r++)
            bias[mc][r] = b1[co0 + mc * 16 + lhi * 4 + r];

    for (int chunk = 0; chunk < 2; chunk++) {
        const int px0 = chunk * 128;
        __syncthreads();
        if (wv < 3) {   // wave wv stages input row y+wv (padded coords)
            const char* src = (const char*)xt +
                (((size_t)(bl * PW) + y + wv) * PW + px0) * 64 + (size_t)l * 16;
            char* dst = (char*)xs + wv * 8448;
#pragma unroll
            for (int i = 0; i < 8; i++) gload16(src + i * 1024, dst + i * 1024);
            if (l < 8) gload16(src + 8192, dst + 8192);
        }
        __syncthreads();

        f32x4 acc[2][4];
#pragma unroll
        for (int t = 0; t < 2; t++)
#pragma unroll
            for (int mc = 0; mc < 4; mc++) acc[t][mc] = (f32x4){0.f, 0.f, 0.f, 0.f};

        // depth-1 prefetched tap loop
        short8 a[4], an[4];
#pragma unroll
        for (int mc = 0; mc < 4; mc++)
            an[mc] = *(const short8*)(w1t + ((size_t)(0 * 4 + lhi) * 384 + co0 + mc * 16 + llo) * 8);
#pragma unroll
        for (int tap = 0; tap < 9; tap++) {
            const int dy = tap / 3, dx = tap % 3;
#pragma unroll
            for (int mc = 0; mc < 4; mc++) a[mc] = an[mc];
            if (tap < 8) {
#pragma unroll
                for (int mc = 0; mc < 4; mc++)
                    an[mc] = *(const short8*)(w1t +
                        ((size_t)((tap + 1) * 4 + lhi) * 384 + co0 + mc * 16 + llo) * 8);
            }
#pragma unroll
            for (int t = 0; t < 2; t++) {
                short8 bf = *(const short8*)&xs[((dy * 132 + wv * 32 + t * 16 + llo + dx) << 5) + (lhi << 3)];
#pragma unroll
                for (int mc = 0; mc < 4; mc++)
                    acc[t][mc] = __builtin_amdgcn_mfma_f32_16x16x32_bf16(a[mc], bf, acc[t][mc], 0, 0, 0);
            }
        }

#pragma unroll
        for (int t = 0; t < 2; t++) {
            int p = y * WW + px0 + wv * 32 + t * 16 + llo;
#pragma unroll
            for (int mc = 0; mc < 4; mc++)
#pragma unroll
                for (int r = 0; r < 4; r++) {
                    int c = co0 + mc * 16 + lhi * 4 + r;
                    int comp = c >> 7, ch = c & 127;
                    qkv[((size_t)(comp * nb + bl) * CMID + ch) * NPIX + p] =
                        f2u(acc[t][mc][r] + bias[mc][r]);
                }
        }
    }
}

// ---- softmax stats over k rows ----
__global__ __launch_bounds__(256) void k_stats(
    const unsigned short* __restrict__ qkv, float* __restrict__ rmax,
    float* __restrict__ rinv, int b0, int nb)
{
    const int bl = blockIdx.x >> 7;
    const int r  = blockIdx.x & 127;
    const int row = (b0 + bl) * CMID + r;
    const ushort4* kp = (const ushort4*)(qkv + ((size_t)(nb + bl) * CMID + r) * NPIX);
    __shared__ float red[256];
    const int tx = threadIdx.x;

    float m = -3.4e38f;
    for (int i = tx; i < NPIX / 4; i += 256) {
        ushort4 u = kp[i];
        m = fmaxf(m, fmaxf(fmaxf(u2f(u.x), u2f(u.y)), fmaxf(u2f(u.z), u2f(u.w))));
    }
    red[tx] = m;
    __syncthreads();
    for (int s = 128; s > 0; s >>= 1) {
        if (tx < s) red[tx] = fmaxf(red[tx], red[tx + s]);
        __syncthreads();
    }
    m = red[0];
    __syncthreads();
    float sum = 0.f;
    for (int i = tx; i < NPIX / 4; i += 256) {
        ushort4 u = kp[i];
        sum += __expf(u2f(u.x) - m) + __expf(u2f(u.y) - m) +
               __expf(u2f(u.z) - m) + __expf(u2f(u.w) - m);
    }
    red[tx] = sum;
    __syncthreads();
    for (int s = 128; s > 0; s >>= 1) {
        if (tx < s) red[tx] += red[tx + s];
        __syncthreads();
    }
    if (tx == 0) { rmax[row] = m; rinv[row] = 1.f / red[0]; }
}

// ---- weights[bh,d,e] = sum_n q[d,n] * exp(k[e,n]-m)*z ----
__global__ __launch_bounds__(256) void k_weights(
    const unsigned short* __restrict__ qkv, const float* __restrict__ rmax,
    const float* __restrict__ rinv, float* __restrict__ wts, int b0, int nb)
{
    const int bl = blockIdx.y >> 2, h = blockIdx.y & 3;
    const int bh = (b0 + bl) * 4 + h;
    const int wv = threadIdx.x >> 6, lane = threadIdx.x & 63;
    const int n0 = blockIdx.x * 1024 + wv * 256;
    const int d0 = (lane >> 3) * 4, e0 = (lane & 7) * 4;

    size_t qch[4], kch[4];
    float me[4], ze[4];
#pragma unroll
    for (int i = 0; i < 4; i++) {
        qch[i] = ((size_t)bl * CMID + h * 32 + d0 + i) * NPIX;
        kch[i] = ((size_t)(nb + bl) * CMID + h * 32 + e0 + i) * NPIX;
        me[i]  = rmax[(b0 + bl) * CMID + h * 32 + e0 + i];
        ze[i]  = rinv[(b0 + bl) * CMID + h * 32 + e0 + i];
    }

    float acc[4][4];
#pragma unroll
    for (int i = 0; i < 4; i++)
#pragma unroll
        for (int j = 0; j < 4; j++) acc[i][j] = 0.f;

    for (int nn = 0; nn < 256; nn += 4) {
        int n = n0 + nn;
        float qf[4][4], pf[4][4];
#pragma unroll
        for (int i = 0; i < 4; i++) {
            ushort4 u = *(const ushort4*)(qkv + qch[i] + n);
            qf[i][0] = u2f(u.x); qf[i][1] = u2f(u.y); qf[i][2] = u2f(u.z); qf[i][3] = u2f(u.w);
            ushort4 v = *(const ushort4*)(qkv + kch[i] + n);
            pf[i][0] = __expf(u2f(v.x) - me[i]) * ze[i];
            pf[i][1] = __expf(u2f(v.y) - me[i]) * ze[i];
            pf[i][2] = __expf(u2f(v.z) - me[i]) * ze[i];
            pf[i][3] = __expf(u2f(v.w) - me[i]) * ze[i];
        }
#pragma unroll
        for (int di = 0; di < 4; di++)
#pragma unroll
            for (int j = 0; j < 4; j++)
#pragma unroll
                for (int ei = 0; ei < 4; ei++)
                    acc[di][ei] += qf[di][j] * pf[ei][j];
    }
    float* wp = wts + (size_t)bh * 1024;
#pragma unroll
    for (int di = 0; di < 4; di++)
#pragma unroll
        for (int ei = 0; ei < 4; ei++)
            atomicAdd(&wp[(d0 + di) * 32 + e0 + ei], acc[di][ei]);
}

// ---- at2[bl][1+row][1+col][128] = sum_d W[d,e] v[d,px]  (NHWC, padded) ----
// grid (NPIX/512, nb); thread = 2 px
__global__ __launch_bounds__(256) void k_attnout(
    const unsigned short* __restrict__ qkv, const float* __restrict__ wts,
    unsigned short* __restrict__ at2, int b0, int nb)
{
    const int tx = threadIdx.x, bl = blockIdx.y, b = b0 + bl;
    const int px = blockIdx.x * 512 + tx * 2;
    __shared__ float Wf[4096];
    for (int i = tx; i < 4096; i += 256) Wf[i] = wts[(size_t)b * 4096 + i];
    __syncthreads();

    const unsigned short* vb = qkv + ((size_t)(2 * nb + bl) * CMID) * NPIX;
    const int row = px >> 8, colb = px & 255;
    const size_t obase = ((size_t)(bl * PW + 1 + row) * PW + 1 + colb) * 128;

#pragma unroll
    for (int h = 0; h < 4; h++) {
        float a0[32], a1[32];
#pragma unroll
        for (int e = 0; e < 32; e++) { a0[e] = 0.f; a1[e] = 0.f; }
        const float* Wh = &Wf[h * 1024];
        for (int d = 0; d < 32; d++) {
            unsigned int u = *(const unsigned int*)(vb + (size_t)(h * 32 + d) * NPIX + px);
            float v0 = u2f((unsigned short)(u & 0xffffu));
            float v1 = u2f((unsigned short)(u >> 16));
            const float4* w4 = (const float4*)&Wh[d * 32];
#pragma unroll
            for (int e4 = 0; e4 < 8; e4++) {
                float4 w = w4[e4];
                a0[e4*4+0] += w.x * v0; a1[e4*4+0] += w.x * v1;
                a0[e4*4+1] += w.y * v0; a1[e4*4+1] += w.y * v1;
                a0[e4*4+2] += w.z * v0; a1[e4*4+2] += w.z * v1;
                a0[e4*4+3] += w.w * v0; a1[e4*4+3] += w.w * v1;
            }
        }
        uint4* o0 = (uint4*)(at2 + obase + h * 32);
        uint4* o1 = (uint4*)(at2 + obase + 128 + h * 32);
#pragma unroll
        for (int q = 0; q < 4; q++) {
            o0[q] = make_uint4(pk2(a0[q*8+0], a0[q*8+1]), pk2(a0[q*8+2], a0[q*8+3]),
                               pk2(a0[q*8+4], a0[q*8+5]), pk2(a0[q*8+6], a0[q*8+7]));
            o1[q] = make_uint4(pk2(a1[q*8+0], a1[q*8+1]), pk2(a1[q*8+2], a1[q*8+3]),
                               pk2(a1[q*8+4], a1[q*8+5]), pk2(a1[q*8+6], a1[q*8+7]));
        }
    }
}

// ---- zero at2 borders ---- grid (258, nb)
__global__ __launch_bounds__(256) void k_bord(unsigned short* __restrict__ at2) {
    const int row = blockIdx.x, bl = blockIdx.y, tx = threadIdx.x;
    unsigned int* rp = (unsigned int*)(at2 + ((size_t)(bl * PW + row) * PW) * 128);
    if (row == 0 || row == PW - 1) {
        for (int i = tx; i < PW * 64; i += 256) rp[i] = 0u;
    } else {
        if (tx < 64) rp[tx] = 0u;
        else if (tx < 128) rp[(size_t)(PW - 1) * 64 + tx - 64] = 0u;
    }
}

// ---- conv2: implicit GEMM from NHWC at2 ---- grid (2, 256, nb)
__global__ __launch_bounds__(256, 4) void k_conv2(
    const unsigned short* __restrict__ at2, const short* __restrict__ w2t,
    const float* __restrict__ b2, float* __restrict__ out, int b0, int nb)
{
    const int px0 = blockIdx.x * 128;
    const int y   = blockIdx.y;
    const int bl  = blockIdx.z;
    const int b   = b0 + bl;
    const int tx  = threadIdx.x;
    const int wv  = tx >> 6, l = tx & 63;
    const int lhi = l >> 4, llo = l & 15;

    __shared__ short xs[3 * 132 * 32];   // per-ci-chunk patch, 25344 B

    f32x4 acc[2][2];
#pragma unroll
    for (int t = 0; t < 2; t++)
#pragma unroll
        for (int m = 0; m < 2; m++) acc[t][m] = (f32x4){0.f, 0.f, 0.f, 0.f};

    for (int cc = 0; cc < 4; cc++) {
        __syncthreads();
        if (wv < 3) {
            const char* src = (const char*)at2 +
                (((size_t)(bl * PW) + y + wv) * PW + px0) * 256 + cc * 64 +
                (size_t)(l >> 2) * 256 + (size_t)(l & 3) * 16;
            char* dst = (char*)xs + wv * 8448;
#pragma unroll
            for (int i = 0; i < 8; i++) gload16(src + (size_t)i * 4096, dst + i * 1024);
            if (l < 8) gload16(src + (size_t)8 * 4096, dst + 8192);
        }
        __syncthreads();

        short8 a[2], an[2];
#pragma unroll
        for (int m = 0; m < 2; m++)
            an[m] = *(const short8*)(w2t + ((size_t)(0 * 16 + cc * 4 + lhi) * 32 + m * 16 + llo) * 8);
#pragma unroll
        for (int tap = 0; tap < 9; tap++) {
            const int dy = tap / 3, dx = tap % 3;
#pragma unroll
            for (int m = 0; m < 2; m++) a[m] = an[m];
            if (tap < 8) {
#pragma unroll
                for (int m = 0; m < 2; m++)
                    an[m] = *(const short8*)(w2t +
                        ((size_t)((tap + 1) * 16 + cc * 4 + lhi) * 32 + m * 16 + llo) * 8);
            }
#pragma unroll
            for (int t = 0; t < 2; t++) {
                short8 bf = *(const short8*)&xs[((dy * 132 + wv * 32 + t * 16 + llo + dx) << 5) + (lhi << 3)];
#pragma unroll
                for (int m = 0; m < 2; m++)
                    acc[t][m] = __builtin_amdgcn_mfma_f32_16x16x32_bf16(a[m], bf, acc[t][m], 0, 0, 0);
            }
        }
    }

#pragma unroll
    for (int t = 0; t < 2; t++) {
        int p = y * WW + px0 + wv * 32 + t * 16 + llo;
#pragma unroll
        for (int m = 0; m < 2; m++)
#pragma unroll
            for (int r = 0; r < 4; r++) {
                int co = m * 16 + lhi * 4 + r;
                out[((size_t)b * COUT + co) * NPIX + p] = acc[t][m][r] + b2[co];
            }
    }
}

extern "C" void kernel_launch(void* const* d_in, const int* in_sizes, int n_in,
                              void* d_out, int out_size, void* d_ws, size_t ws_size,
                              hipStream_t stream) {
    const float* x  = (const float*)d_in[0];
    const float* w1 = (const float*)d_in[1];
    const float* b1 = (const float*)d_in[2];
    const float* w2 = (const float*)d_in[3];
    const float* b2 = (const float*)d_in[4];
    float* out = (float*)d_out;

    char* ws = (char*)d_ws;
    float* rmax = (float*)(ws);
    float* rinv = (float*)(ws + 2048);
    float* wts  = (float*)(ws + 4096);
    short* w1t  = (short*)(ws + 69632);    // 221184 B
    short* w2t  = (short*)(ws + 290816);   //  73728 B
    const size_t OFF_XT = 1048576;

    // full path (nb=4) needs 219,415,552 B; fallback per-batch needs 55,640,320 B
    int nb = 4;
    {
        size_t xt_sz  = (size_t)nb * PW * PW * 64;
        size_t total  = OFF_XT + xt_sz + (size_t)3 * nb * CMID * NPIX * 2;
        if (ws_size < total) nb = 1;
    }
    const size_t xt_sz   = (size_t)nb * PW * PW * 64;
    const size_t qkv_off = OFF_XT + xt_sz;
    const size_t q_sz    = (size_t)nb * CMID * NPIX * 2;
    const size_t at2_off = qkv_off + q_sz - (size_t)nb * PW * PW * 256;

    unsigned short* xt  = (unsigned short*)(ws + OFF_XT);
    unsigned short* qkv = (unsigned short*)(ws + qkv_off);
    unsigned short* at2 = (unsigned short*)(ws + at2_off);

    k_zero<<<dim3(64), 256, 0, stream>>>(wts, 16 * 1024);
    k_w1t <<<dim3(9),  256, 0, stream>>>(w1, w1t);
    k_w2t <<<dim3(9),  256, 0, stream>>>(w2, w2t);

    for (int b0 = 0; b0 < B_; b0 += nb) {
        k_xt     <<<dim3(PW, nb),        256, 0, stream>>>(x, xt, b0);
        k_conv1  <<<dim3(6, HH, nb),     256, 0, stream>>>(xt, w1t, b1, qkv, nb);
        k_stats  <<<dim3(nb * CMID),     256, 0, stream>>>(qkv, rmax, rinv, b0, nb);
        k_weights<<<dim3(64, nb * 4),    256, 0, stream>>>(qkv, rmax, rinv, wts, b0, nb);
        k_bord   <<<dim3(PW, nb),        256, 0, stream>>>(at2);
        k_attnout<<<dim3(NPIX / 512, nb),256, 0, stream>>>(qkv, wts, at2, b0, nb);
        k_conv2  <<<dim3(2, HH, nb),     256, 0, stream>>>(at2, w2t, b2, out, b0, nb);
    }
}

// Round 6
// 625.302 us; speedup vs baseline: 5.2696x; 1.3885x over previous
//
#include <hip/hip_runtime.h>
#include <hip/hip_bf16.h>

typedef __hip_bfloat16 bf16;
typedef __attribute__((ext_vector_type(8))) short short8;
typedef __attribute__((ext_vector_type(4))) float f32x4;

#define B_    4
#define CIN   32
#define HH    256
#define WW    256
#define C1    384
#define NPIX  65536
#define CMID  128
#define COUT  32
#define PW    258   // padded spatial width

static __device__ __forceinline__ float u2f(unsigned short u) {
    unsigned int x = ((unsigned int)u) << 16;
    return __uint_as_float(x);
}
static __device__ __forceinline__ unsigned short f2u(float f) {
    bf16 h = __float2bfloat16(f);
    return __builtin_bit_cast(unsigned short, h);
}
static __device__ __forceinline__ unsigned int pk2(float lo, float hi) {
    return (unsigned int)f2u(lo) | ((unsigned int)f2u(hi) << 16);
}
// async global->LDS, 16B per lane; dst is wave-uniform base (HW adds lane*16)
static __device__ __forceinline__ void gload16(const void* src, void* dst) {
    __builtin_amdgcn_global_load_lds(
        (const __attribute__((address_space(1))) void*)src,
        (__attribute__((address_space(3))) void*)dst, 16, 0, 0);
}

__global__ __launch_bounds__(256) void k_zero(float* __restrict__ p, int n) {
    int i = blockIdx.x * 256 + threadIdx.x;
    if (i < n) p[i] = 0.f;
}

// ---- w1(384,32,3,3) fp32 -> w1t[tap][cihi4][co384][8] bf16 ----
__global__ __launch_bounds__(256) void k_w1t(const float* __restrict__ w1, short* __restrict__ w1t) {
    const int tap = blockIdx.x;
    for (int i = threadIdx.x; i < 384 * 32; i += 256) {
        int co = i >> 5, cij = i & 31;
        w1t[((size_t)(tap * 4 + (cij >> 3)) * 384 + co) * 8 + (cij & 7)] =
            (short)f2u(w1[(size_t)i * 9 + tap]);
    }
}
// ---- w2(32,128,3,3) fp32 -> w2t[tap][cihi16][co32][8] bf16 ----
__global__ __launch_bounds__(256) void k_w2t(const float* __restrict__ w2, short* __restrict__ w2t) {
    const int tap = blockIdx.x;
    for (int i = threadIdx.x; i < 32 * 128; i += 256) {
        int co = i >> 7, cij = i & 127;
        w2t[((size_t)(tap * 16 + (cij >> 3)) * 32 + co) * 8 + (cij & 7)] =
            (short)f2u(w2[(size_t)i * 9 + tap]);
    }
}

// ---- x(b,32,256,256) fp32 -> xt[bl][row][col][32] bf16, zero-padded borders ----
__global__ __launch_bounds__(256) void k_xt(const float* __restrict__ x,
                                            unsigned short* __restrict__ xt, int b0) {
    const int row = blockIdx.x, bl = blockIdx.y, b = b0 + bl;
    const int tx = threadIdx.x;
    unsigned int* rp = (unsigned int*)(xt + ((size_t)(bl * PW + row) * PW) * 32);
    if (row == 0 || row == PW - 1) {
        for (int i = tx; i < PW * 16; i += 256) rp[i] = 0u;
        return;
    }
    if (tx < 2) {
        unsigned int* cp = rp + (size_t)(tx * (PW - 1)) * 16;
#pragma unroll
        for (int i = 0; i < 16; i++) cp[i] = 0u;
    }
    const int col = tx + 1;
    const size_t px = (size_t)(row - 1) * WW + tx;
    unsigned int pk[16];
#pragma unroll
    for (int c2 = 0; c2 < 16; c2++) {
        float v0 = x[((size_t)b * CIN + 2 * c2) * NPIX + px];
        float v1 = x[((size_t)b * CIN + 2 * c2 + 1) * NPIX + px];
        pk[c2] = pk2(v0, v1);
    }
    uint4* dst = (uint4*)(rp + (size_t)col * 16);
#pragma unroll
    for (int q = 0; q < 4; q++)
        dst[q] = make_uint4(pk[q * 4], pk[q * 4 + 1], pk[q * 4 + 2], pk[q * 4 + 3]);
}

// ---- conv1: implicit GEMM; 1D grid with XCD swizzle; coalesced LDS-staged epilogue ----
// nblk = 6*256*nb; per XCD: 32 y-rows, inner (y, co-block, bl)
__global__ __launch_bounds__(256, 3) void k_conv1(
    const unsigned short* __restrict__ xt, const short* __restrict__ w1t,
    const float* __restrict__ b1, unsigned short* __restrict__ qkv, int nb)
{
    const int bid = blockIdx.x;
    const int xcd = bid & 7;
    const int i   = bid >> 3;
    const int per_y = 6 * nb;
    const int y  = xcd * 32 + i / per_y;
    const int j  = i % per_y;
    const int co0 = (j % 6) * 64;
    const int bl  = j / 6;

    const int tx  = threadIdx.x;
    const int wv  = tx >> 6, l = tx & 63;
    const int lhi = l >> 4, llo = l & 15;

    __shared__ short xs[3 * 132 * 32];   // 25344 B
    __shared__ short os[64][136];        // 17408 B  (output staging, padded)

    float bias[4][4];
#pragma unroll
    for (int mc = 0; mc < 4; mc++)
#pragma unroll
        for (int r = 0; r < 4; r++)
            bias[mc][r] = b1[co0 + mc * 16 + lhi * 4 + r];

    for (int chunk = 0; chunk < 2; chunk++) {
        const int px0 = chunk * 128;
        __syncthreads();
        if (wv < 3) {
            const char* src = (const char*)xt +
                (((size_t)(bl * PW) + y + wv) * PW + px0) * 64 + (size_t)l * 16;
            char* dst = (char*)xs + wv * 8448;
#pragma unroll
            for (int q = 0; q < 8; q++) gload16(src + q * 1024, dst + q * 1024);
            if (l < 8) gload16(src + 8192, dst + 8192);
        }
        __syncthreads();

        f32x4 acc[2][4];
#pragma unroll
        for (int t = 0; t < 2; t++)
#pragma unroll
            for (int mc = 0; mc < 4; mc++) acc[t][mc] = (f32x4){0.f, 0.f, 0.f, 0.f};

        short8 a[4], an[4];
#pragma unroll
        for (int mc = 0; mc < 4; mc++)
            an[mc] = *(const short8*)(w1t + ((size_t)lhi * 384 + co0 + mc * 16 + llo) * 8);
#pragma unroll
        for (int tap = 0; tap < 9; tap++) {
            const int dy = tap / 3, dx = tap % 3;
#pragma unroll
            for (int mc = 0; mc < 4; mc++) a[mc] = an[mc];
            if (tap < 8) {
#pragma unroll
                for (int mc = 0; mc < 4; mc++)
                    an[mc] = *(const short8*)(w1t +
                        ((size_t)((tap + 1) * 4 + lhi) * 384 + co0 + mc * 16 + llo) * 8);
            }
#pragma unroll
            for (int t = 0; t < 2; t++) {
                short8 bfr = *(const short8*)&xs[((dy * 132 + wv * 32 + t * 16 + llo + dx) << 5) + (lhi << 3)];
#pragma unroll
                for (int mc = 0; mc < 4; mc++)
                    acc[t][mc] = __builtin_amdgcn_mfma_f32_16x16x32_bf16(a[mc], bfr, acc[t][mc], 0, 0, 0);
            }
        }

        // stage output tile in LDS (2-way-conflict writes, free)
#pragma unroll
        for (int t = 0; t < 2; t++)
#pragma unroll
            for (int mc = 0; mc < 4; mc++)
#pragma unroll
                for (int r = 0; r < 4; r++)
                    os[mc * 16 + lhi * 4 + r][wv * 32 + t * 16 + llo] =
                        (short)f2u(acc[t][mc][r] + bias[mc][r]);
        __syncthreads();

        // dense store: thread -> 64B of one channel row
        {
            const int chl = tx >> 2;
            const int c   = co0 + chl;
            const int comp = c >> 7, chn = c & 127;
            const uint4* ls = (const uint4*)&os[chl][(tx & 3) * 32];
            uint4 v0 = ls[0], v1 = ls[1], v2 = ls[2], v3 = ls[3];
            uint4* gp = (uint4*)(qkv + ((size_t)(comp * nb + bl) * CMID + chn) * NPIX
                                 + y * WW + px0 + (tx & 3) * 32);
            gp[0] = v0; gp[1] = v1; gp[2] = v2; gp[3] = v3;
        }
    }
}

// ---- softmax stats over k rows ----
__global__ __launch_bounds__(256) void k_stats(
    const unsigned short* __restrict__ qkv, float* __restrict__ rmax,
    float* __restrict__ rinv, int b0, int nb)
{
    const int bl = blockIdx.x >> 7;
    const int r  = blockIdx.x & 127;
    const int row = (b0 + bl) * CMID + r;
    const ushort4* kp = (const ushort4*)(qkv + ((size_t)(nb + bl) * CMID + r) * NPIX);
    __shared__ float red[256];
    const int tx = threadIdx.x;

    float m = -3.4e38f;
    for (int i = tx; i < NPIX / 4; i += 256) {
        ushort4 u = kp[i];
        m = fmaxf(m, fmaxf(fmaxf(u2f(u.x), u2f(u.y)), fmaxf(u2f(u.z), u2f(u.w))));
    }
    red[tx] = m;
    __syncthreads();
    for (int s = 128; s > 0; s >>= 1) {
        if (tx < s) red[tx] = fmaxf(red[tx], red[tx + s]);
        __syncthreads();
    }
    m = red[0];
    __syncthreads();
    float sum = 0.f;
    for (int i = tx; i < NPIX / 4; i += 256) {
        ushort4 u = kp[i];
        sum += __expf(u2f(u.x) - m) + __expf(u2f(u.y) - m) +
               __expf(u2f(u.z) - m) + __expf(u2f(u.w) - m);
    }
    red[tx] = sum;
    __syncthreads();
    for (int s = 128; s > 0; s >>= 1) {
        if (tx < s) red[tx] += red[tx + s];
        __syncthreads();
    }
    if (tx == 0) { rmax[row] = m; rinv[row] = 1.f / red[0]; }
}

// ---- weights[bh,d,e] = sum_n q[d,n] * exp(k[e,n]-m)*z ----
__global__ __launch_bounds__(256) void k_weights(
    const unsigned short* __restrict__ qkv, const float* __restrict__ rmax,
    const float* __restrict__ rinv, float* __restrict__ wts, int b0, int nb)
{
    const int bl = blockIdx.y >> 2, h = blockIdx.y & 3;
    const int bh = (b0 + bl) * 4 + h;
    const int wv = threadIdx.x >> 6, lane = threadIdx.x & 63;
    const int n0 = blockIdx.x * 1024 + wv * 256;
    const int d0 = (lane >> 3) * 4, e0 = (lane & 7) * 4;

    size_t qch[4], kch[4];
    float me[4], ze[4];
#pragma unroll
    for (int i = 0; i < 4; i++) {
        qch[i] = ((size_t)bl * CMID + h * 32 + d0 + i) * NPIX;
        kch[i] = ((size_t)(nb + bl) * CMID + h * 32 + e0 + i) * NPIX;
        me[i]  = rmax[(b0 + bl) * CMID + h * 32 + e0 + i];
        ze[i]  = rinv[(b0 + bl) * CMID + h * 32 + e0 + i];
    }

    float acc[4][4];
#pragma unroll
    for (int i = 0; i < 4; i++)
#pragma unroll
        for (int j = 0; j < 4; j++) acc[i][j] = 0.f;

    for (int nn = 0; nn < 256; nn += 4) {
        int n = n0 + nn;
        float qf[4][4], pf[4][4];
#pragma unroll
        for (int i = 0; i < 4; i++) {
            ushort4 u = *(const ushort4*)(qkv + qch[i] + n);
            qf[i][0] = u2f(u.x); qf[i][1] = u2f(u.y); qf[i][2] = u2f(u.z); qf[i][3] = u2f(u.w);
            ushort4 v = *(const ushort4*)(qkv + kch[i] + n);
            pf[i][0] = __expf(u2f(v.x) - me[i]) * ze[i];
            pf[i][1] = __expf(u2f(v.y) - me[i]) * ze[i];
            pf[i][2] = __expf(u2f(v.z) - me[i]) * ze[i];
            pf[i][3] = __expf(u2f(v.w) - me[i]) * ze[i];
        }
#pragma unroll
        for (int di = 0; di < 4; di++)
#pragma unroll
            for (int j = 0; j < 4; j++)
#pragma unroll
                for (int ei = 0; ei < 4; ei++)
                    acc[di][ei] += qf[di][j] * pf[ei][j];
    }
    float* wp = wts + (size_t)bh * 1024;
#pragma unroll
    for (int di = 0; di < 4; di++)
#pragma unroll
        for (int ei = 0; ei < 4; ei++)
            atomicAdd(&wp[(d0 + di) * 32 + e0 + ei], acc[di][ei]);
}

// ---- at2[bl][1+row][1+col][128] = sum_d W[d,e] v[d,px] ----
__global__ __launch_bounds__(256) void k_attnout(
    const unsigned short* __restrict__ qkv, const float* __restrict__ wts,
    unsigned short* __restrict__ at2, int b0, int nb)
{
    const int tx = threadIdx.x, bl = blockIdx.y, b = b0 + bl;
    const int px = blockIdx.x * 512 + tx * 2;
    __shared__ float Wf[4096];
    for (int i = tx; i < 4096; i += 256) Wf[i] = wts[(size_t)b * 4096 + i];
    __syncthreads();

    const unsigned short* vb = qkv + ((size_t)(2 * nb + bl) * CMID) * NPIX;
    const int row = px >> 8, colb = px & 255;
    const size_t obase = ((size_t)(bl * PW + 1 + row) * PW + 1 + colb) * 128;

#pragma unroll
    for (int h = 0; h < 4; h++) {
        float a0[32], a1[32];
#pragma unroll
        for (int e = 0; e < 32; e++) { a0[e] = 0.f; a1[e] = 0.f; }
        const float* Wh = &Wf[h * 1024];
        for (int d = 0; d < 32; d++) {
            unsigned int u = *(const unsigned int*)(vb + (size_t)(h * 32 + d) * NPIX + px);
            float v0 = u2f((unsigned short)(u & 0xffffu));
            float v1 = u2f((unsigned short)(u >> 16));
            const float4* w4 = (const float4*)&Wh[d * 32];
#pragma unroll
            for (int e4 = 0; e4 < 8; e4++) {
                float4 w = w4[e4];
                a0[e4*4+0] += w.x * v0; a1[e4*4+0] += w.x * v1;
                a0[e4*4+1] += w.y * v0; a1[e4*4+1] += w.y * v1;
                a0[e4*4+2] += w.z * v0; a1[e4*4+2] += w.z * v1;
                a0[e4*4+3] += w.w * v0; a1[e4*4+3] += w.w * v1;
            }
        }
        uint4* o0 = (uint4*)(at2 + obase + h * 32);
        uint4* o1 = (uint4*)(at2 + obase + 128 + h * 32);
#pragma unroll
        for (int q = 0; q < 4; q++) {
            o0[q] = make_uint4(pk2(a0[q*8+0], a0[q*8+1]), pk2(a0[q*8+2], a0[q*8+3]),
                               pk2(a0[q*8+4], a0[q*8+5]), pk2(a0[q*8+6], a0[q*8+7]));
            o1[q] = make_uint4(pk2(a1[q*8+0], a1[q*8+1]), pk2(a1[q*8+2], a1[q*8+3]),
                               pk2(a1[q*8+4], a1[q*8+5]), pk2(a1[q*8+6], a1[q*8+7]));
        }
    }
}

// ---- zero at2 borders ----
__global__ __launch_bounds__(256) void k_bord(unsigned short* __restrict__ at2) {
    const int row = blockIdx.x, bl = blockIdx.y, tx = threadIdx.x;
    unsigned int* rp = (unsigned int*)(at2 + ((size_t)(bl * PW + row) * PW) * 128);
    if (row == 0 || row == PW - 1) {
        for (int i = tx; i < PW * 64; i += 256) rp[i] = 0u;
    } else {
        if (tx < 64) rp[tx] = 0u;
        else if (tx < 128) rp[(size_t)(PW - 1) * 64 + tx - 64] = 0u;
    }
}

// ---- conv2: implicit GEMM; 1D grid with XCD swizzle; coalesced epilogue ----
// nblk = 2*256*nb; per XCD: 32 y-rows, inner (y, chunk, bl)
__global__ __launch_bounds__(256, 3) void k_conv2(
    const unsigned short* __restrict__ at2, const short* __restrict__ w2t,
    const float* __restrict__ b2, float* __restrict__ out, int b0, int nb)
{
    const int bid = blockIdx.x;
    const int xcd = bid & 7;
    const int i   = bid >> 3;
    const int per_y = 2 * nb;
    const int y   = xcd * 32 + i / per_y;
    const int j   = i % per_y;
    const int px0 = (j & 1) * 128;
    const int bl  = j >> 1;
    const int bb  = b0 + bl;

    const int tx  = threadIdx.x;
    const int wv  = tx >> 6, l = tx & 63;
    const int lhi = l >> 4, llo = l & 15;

    __shared__ short xs[3 * 132 * 32];   // 25344 B
    __shared__ float osf[32][132];       // 16896 B

    float bias[2][4];
#pragma unroll
    for (int m = 0; m < 2; m++)
#pragma unroll
        for (int r = 0; r < 4; r++)
            bias[m][r] = b2[m * 16 + lhi * 4 + r];

    f32x4 acc[2][2];
#pragma unroll
    for (int t = 0; t < 2; t++)
#pragma unroll
        for (int m = 0; m < 2; m++) acc[t][m] = (f32x4){0.f, 0.f, 0.f, 0.f};

    for (int cc = 0; cc < 4; cc++) {
        __syncthreads();
        if (wv < 3) {
            const char* src = (const char*)at2 +
                (((size_t)(bl * PW) + y + wv) * PW + px0) * 256 + cc * 64 +
                (size_t)(l >> 2) * 256 + (size_t)(l & 3) * 16;
            char* dst = (char*)xs + wv * 8448;
#pragma unroll
            for (int q = 0; q < 8; q++) gload16(src + (size_t)q * 4096, dst + q * 1024);
            if (l < 8) gload16(src + (size_t)8 * 4096, dst + 8192);
        }
        __syncthreads();

        short8 a[2], an[2];
#pragma unroll
        for (int m = 0; m < 2; m++)
            an[m] = *(const short8*)(w2t + ((size_t)(cc * 4 + lhi) * 32 + m * 16 + llo) * 8);
#pragma unroll
        for (int tap = 0; tap < 9; tap++) {
            const int dy = tap / 3, dx = tap % 3;
#pragma unroll
            for (int m = 0; m < 2; m++) a[m] = an[m];
            if (tap < 8) {
#pragma unroll
                for (int m = 0; m < 2; m++)
                    an[m] = *(const short8*)(w2t +
                        ((size_t)((tap + 1) * 16 + cc * 4 + lhi) * 32 + m * 16 + llo) * 8);
            }
#pragma unroll
            for (int t = 0; t < 2; t++) {
                short8 bfr = *(const short8*)&xs[((dy * 132 + wv * 32 + t * 16 + llo + dx) << 5) + (lhi << 3)];
#pragma unroll
                for (int m = 0; m < 2; m++)
                    acc[t][m] = __builtin_amdgcn_mfma_f32_16x16x32_bf16(a[m], bfr, acc[t][m], 0, 0, 0);
            }
        }
    }

    // LDS-staged coalesced fp32 epilogue
#pragma unroll
    for (int t = 0; t < 2; t++)
#pragma unroll
        for (int m = 0; m < 2; m++)
#pragma unroll
            for (int r = 0; r < 4; r++)
                osf[m * 16 + lhi * 4 + r][wv * 32 + t * 16 + llo] = acc[t][m][r] + bias[m][r];
    __syncthreads();
    {
        const int chl = tx >> 3;
        const int pxo = (tx & 7) * 16;
        const uint4* ls = (const uint4*)&osf[chl][pxo];
        uint4 v0 = ls[0], v1 = ls[1], v2 = ls[2], v3 = ls[3];
        uint4* gp = (uint4*)(out + ((size_t)bb * COUT + chl) * NPIX + y * WW + px0 + pxo);
        gp[0] = v0; gp[1] = v1; gp[2] = v2; gp[3] = v3;
    }
}

extern "C" void kernel_launch(void* const* d_in, const int* in_sizes, int n_in,
                              void* d_out, int out_size, void* d_ws, size_t ws_size,
                              hipStream_t stream) {
    const float* x  = (const float*)d_in[0];
    const float* w1 = (const float*)d_in[1];
    const float* b1 = (const float*)d_in[2];
    const float* w2 = (const float*)d_in[3];
    const float* b2 = (const float*)d_in[4];
    float* out = (float*)d_out;

    char* ws = (char*)d_ws;
    float* rmax = (float*)(ws);
    float* rinv = (float*)(ws + 2048);
    float* wts  = (float*)(ws + 4096);
    short* w1t  = (short*)(ws + 69632);
    short* w2t  = (short*)(ws + 290816);
    const size_t OFF_XT = 1048576;

    int nb = 4;
    {
        size_t xt_sz  = (size_t)nb * PW * PW * 64;
        size_t total  = OFF_XT + xt_sz + (size_t)3 * nb * CMID * NPIX * 2;
        if (ws_size < total) nb = 1;
    }
    const size_t xt_sz   = (size_t)nb * PW * PW * 64;
    const size_t qkv_off = OFF_XT + xt_sz;
    const size_t q_sz    = (size_t)nb * CMID * NPIX * 2;
    const size_t at2_off = qkv_off + q_sz - (size_t)nb * PW * PW * 256;

    unsigned short* xt  = (unsigned short*)(ws + OFF_XT);
    unsigned short* qkv = (unsigned short*)(ws + qkv_off);
    unsigned short* at2 = (unsigned short*)(ws + at2_off);

    k_zero<<<dim3(64), 256, 0, stream>>>(wts, 16 * 1024);
    k_w1t <<<dim3(9),  256, 0, stream>>>(w1, w1t);
    k_w2t <<<dim3(9),  256, 0, stream>>>(w2, w2t);

    for (int b0 = 0; b0 < B_; b0 += nb) {
        k_xt     <<<dim3(PW, nb),         256, 0, stream>>>(x, xt, b0);
        k_conv1  <<<dim3(6 * HH * nb),    256, 0, stream>>>(xt, w1t, b1, qkv, nb);
        k_stats  <<<dim3(nb * CMID),      256, 0, stream>>>(qkv, rmax, rinv, b0, nb);
        k_weights<<<dim3(64, nb * 4),     256, 0, stream>>>(qkv, rmax, rinv, wts, b0, nb);
        k_bord   <<<dim3(PW, nb),         256, 0, stream>>>(at2);
        k_attnout<<<dim3(NPIX / 512, nb), 256, 0, stream>>>(qkv, wts, at2, b0, nb);
        k_conv2  <<<dim3(2 * HH * nb),    256, 0, stream>>>(at2, w2t, b2, out, b0, nb);
    }
}

// Round 7
// 487.128 us; speedup vs baseline: 6.7643x; 1.2836x over previous
//
#include <hip/hip_runtime.h>
#include <hip/hip_bf16.h>

typedef __hip_bfloat16 bf16;
typedef __attribute__((ext_vector_type(8))) short short8;
typedef __attribute__((ext_vector_type(4))) float f32x4;

#define B_    4
#define CIN   32
#define HH    256
#define WW    256
#define C1    384
#define NPIX  65536
#define CMID  128
#define COUT  32
#define PW    258   // padded spatial width

static __device__ __forceinline__ float u2f(unsigned short u) {
    unsigned int x = ((unsigned int)u) << 16;
    return __uint_as_float(x);
}
static __device__ __forceinline__ unsigned short f2u(float f) {
    bf16 h = __float2bfloat16(f);
    return __builtin_bit_cast(unsigned short, h);
}
static __device__ __forceinline__ unsigned int pk2(float lo, float hi) {
    return (unsigned int)f2u(lo) | ((unsigned int)f2u(hi) << 16);
}
// async global->LDS, 16B per active lane; dst wave-uniform base (HW adds lane*16)
static __device__ __forceinline__ void gload16(const void* src, void* dst) {
    __builtin_amdgcn_global_load_lds(
        (const __attribute__((address_space(1))) void*)src,
        (__attribute__((address_space(3))) void*)dst, 16, 0, 0);
}

__global__ __launch_bounds__(256) void k_zero(float* __restrict__ p, int n) {
    int i = blockIdx.x * 256 + threadIdx.x;
    if (i < n) p[i] = 0.f;
}

// ---- w1(384,32,3,3) fp32 -> w1t[tap][cihi4][co384][8] bf16 ----
__global__ __launch_bounds__(256) void k_w1t(const float* __restrict__ w1, short* __restrict__ w1t) {
    const int tap = blockIdx.x;
    for (int i = threadIdx.x; i < 384 * 32; i += 256) {
        int co = i >> 5, cij = i & 31;
        w1t[((size_t)(tap * 4 + (cij >> 3)) * 384 + co) * 8 + (cij & 7)] =
            (short)f2u(w1[(size_t)i * 9 + tap]);
    }
}
// ---- w2(32,128,3,3) fp32 -> w2t[tap][cihi16][co32][8] bf16 ----
__global__ __launch_bounds__(256) void k_w2t(const float* __restrict__ w2, short* __restrict__ w2t) {
    const int tap = blockIdx.x;
    for (int i = threadIdx.x; i < 32 * 128; i += 256) {
        int co = i >> 7, cij = i & 127;
        w2t[((size_t)(tap * 16 + (cij >> 3)) * 32 + co) * 8 + (cij & 7)] =
            (short)f2u(w2[(size_t)i * 9 + tap]);
    }
}

// ---- x(b,32,256,256) fp32 -> xt[bl][row][col][32] bf16, zero-padded borders ----
__global__ __launch_bounds__(256) void k_xt(const float* __restrict__ x,
                                            unsigned short* __restrict__ xt, int b0) {
    const int row = blockIdx.x, bl = blockIdx.y, b = b0 + bl;
    const int tx = threadIdx.x;
    unsigned int* rp = (unsigned int*)(xt + ((size_t)(bl * PW + row) * PW) * 32);
    if (row == 0 || row == PW - 1) {
        for (int i = tx; i < PW * 16; i += 256) rp[i] = 0u;
        return;
    }
    if (tx < 2) {
        unsigned int* cp = rp + (size_t)(tx * (PW - 1)) * 16;
#pragma unroll
        for (int i = 0; i < 16; i++) cp[i] = 0u;
    }
    const int col = tx + 1;
    const size_t px = (size_t)(row - 1) * WW + tx;
    unsigned int pk[16];
#pragma unroll
    for (int c2 = 0; c2 < 16; c2++) {
        float v0 = x[((size_t)b * CIN + 2 * c2) * NPIX + px];
        float v1 = x[((size_t)b * CIN + 2 * c2 + 1) * NPIX + px];
        pk[c2] = pk2(v0, v1);
    }
    uint4* dst = (uint4*)(rp + (size_t)col * 16);
#pragma unroll
    for (int q = 0; q < 4; q++)
        dst[q] = make_uint4(pk[q * 4], pk[q * 4 + 1], pk[q * 4 + 2], pk[q * 4 + 3]);
}

// ---- conv1: merged-co implicit GEMM. Block = (y, 128px chunk), all 384 co in 6 groups ----
// grid: 2*256*nb. LDS: xs 25344 + wt 36864 + os 17408 = 79616 B -> 2 blocks/CU
__global__ __launch_bounds__(256, 2) void k_conv1(
    const unsigned short* __restrict__ xt, const short* __restrict__ w1t,
    const float* __restrict__ b1, unsigned short* __restrict__ qkv, int nb)
{
    const int bid = blockIdx.x;
    const int chunk = bid & 1;
    const int y   = (bid >> 1) & 255;
    const int bl  = bid >> 9;
    const int px0 = chunk * 128;
    const int tx  = threadIdx.x;
    const int wv  = tx >> 6, l = tx & 63;
    const int lhi = l >> 4, llo = l & 15;

    __shared__ short xs[3 * 132 * 32];   // [row][col132][ci32]
    __shared__ short wt[9][4][64][8];    // [tap][ci_hi][co64][ci_lo]
    __shared__ short os[64][136];        // output staging

    // prologue: stage x patch (waves 0-2) + weight tile cog0 (all waves, 9 segs each)
    if (wv < 3) {
        const char* src = (const char*)xt +
            (((size_t)(bl * PW) + y + wv) * PW + px0) * 64 + (size_t)l * 16;
        char* dst = (char*)xs + wv * 8448;
#pragma unroll
        for (int q = 0; q < 8; q++) gload16(src + q * 1024, dst + q * 1024);
        if (l < 8) gload16(src + 8192, dst + 8192);
    }
#pragma unroll
    for (int i = 0; i < 9; i++) {
        int s = wv * 9 + i;
        int tap = s >> 2, ch = s & 3;
        const char* src = (const char*)w1t + ((size_t)(tap * 4 + ch) * 384) * 16 + (size_t)l * 16;
        gload16(src, (char*)&wt[tap][ch][0][0]);
    }
    __syncthreads();

    for (int cog = 0; cog < 6; cog++) {
        const int co0 = cog * 64;
        float bias[4][4];
#pragma unroll
        for (int mc = 0; mc < 4; mc++)
#pragma unroll
            for (int r = 0; r < 4; r++)
                bias[mc][r] = b1[co0 + mc * 16 + lhi * 4 + r];

        f32x4 acc[2][4];
#pragma unroll
        for (int t = 0; t < 2; t++)
#pragma unroll
            for (int mc = 0; mc < 4; mc++) acc[t][mc] = (f32x4){0.f, 0.f, 0.f, 0.f};

#pragma unroll
        for (int tap = 0; tap < 9; tap++) {
            const int dy = tap / 3, dx = tap % 3;
            short8 a[4];
#pragma unroll
            for (int mc = 0; mc < 4; mc++)
                a[mc] = *(const short8*)&wt[tap][lhi][mc * 16 + llo][0];
#pragma unroll
            for (int t = 0; t < 2; t++) {
                short8 bfr = *(const short8*)&xs[((dy * 132 + wv * 32 + t * 16 + llo + dx) << 5) + (lhi << 3)];
#pragma unroll
                for (int mc = 0; mc < 4; mc++)
                    acc[t][mc] = __builtin_amdgcn_mfma_f32_16x16x32_bf16(a[mc], bfr, acc[t][mc], 0, 0, 0);
            }
        }
        __syncthreads();   // wt[cog] reads done; previous store's os reads done

        // stage output tile in LDS
#pragma unroll
        for (int t = 0; t < 2; t++)
#pragma unroll
            for (int mc = 0; mc < 4; mc++)
#pragma unroll
                for (int r = 0; r < 4; r++)
                    os[mc * 16 + lhi * 4 + r][wv * 32 + t * 16 + llo] =
                        (short)f2u(acc[t][mc][r] + bias[mc][r]);

        // prefetch next weight tile
        if (cog < 5) {
#pragma unroll
            for (int i = 0; i < 9; i++) {
                int s = wv * 9 + i;
                int tap = s >> 2, ch = s & 3;
                const char* src = (const char*)w1t +
                    ((size_t)(tap * 4 + ch) * 384 + co0 + 64) * 16 + (size_t)l * 16;
                gload16(src, (char*)&wt[tap][ch][0][0]);
            }
        }
        __syncthreads();   // os visible + wt prefetch drained (vmcnt0 at barrier)

        // coalesced store: 16 lanes x 16B = 256B contiguous per channel per instr
#pragma unroll
        for (int p = 0; p < 4; p++) {
            int chl = p * 16 + (tx >> 4);
            int c = co0 + chl;
            int comp = c >> 7, chn = c & 127;
            uint4 v = *(const uint4*)&os[chl][(tx & 15) * 8];
            *(uint4*)(qkv + ((size_t)(comp * nb + bl) * CMID + chn) * NPIX
                      + y * WW + px0 + (tx & 15) * 8) = v;
        }
    }
}

// ---- single-pass softmax denom: rinv = 1/sum(exp(k)); |k|<~4 so no overflow ----
__global__ __launch_bounds__(256) void k_stats(
    const unsigned short* __restrict__ qkv, float* __restrict__ rinv, int b0, int nb)
{
    const int bl = blockIdx.x >> 7;
    const int r  = blockIdx.x & 127;
    const int row = (b0 + bl) * CMID + r;
    const ushort4* kp = (const ushort4*)(qkv + ((size_t)(nb + bl) * CMID + r) * NPIX);
    __shared__ float red[256];
    const int tx = threadIdx.x;

    float sum = 0.f;
    for (int i = tx; i < NPIX / 4; i += 256) {
        ushort4 u = kp[i];
        sum += __expf(u2f(u.x)) + __expf(u2f(u.y)) + __expf(u2f(u.z)) + __expf(u2f(u.w));
    }
    red[tx] = sum;
    __syncthreads();
    for (int s = 128; s > 0; s >>= 1) {
        if (tx < s) red[tx] += red[tx + s];
        __syncthreads();
    }
    if (tx == 0) rinv[row] = 1.f / red[0];
}

// ---- weights[bh,d,e] = sum_n q[d,n] * exp(k[e,n])*z ----
__global__ __launch_bounds__(256) void k_weights(
    const unsigned short* __restrict__ qkv, const float* __restrict__ rinv,
    float* __restrict__ wts, int b0, int nb)
{
    const int bl = blockIdx.y >> 2, h = blockIdx.y & 3;
    const int bh = (b0 + bl) * 4 + h;
    const int wv = threadIdx.x >> 6, lane = threadIdx.x & 63;
    const int n0 = blockIdx.x * 1024 + wv * 256;
    const int d0 = (lane >> 3) * 4, e0 = (lane & 7) * 4;

    size_t qch[4], kch[4];
    float ze[4];
#pragma unroll
    for (int i = 0; i < 4; i++) {
        qch[i] = ((size_t)bl * CMID + h * 32 + d0 + i) * NPIX;
        kch[i] = ((size_t)(nb + bl) * CMID + h * 32 + e0 + i) * NPIX;
        ze[i]  = rinv[(b0 + bl) * CMID + h * 32 + e0 + i];
    }

    float acc[4][4];
#pragma unroll
    for (int i = 0; i < 4; i++)
#pragma unroll
        for (int j = 0; j < 4; j++) acc[i][j] = 0.f;

    for (int nn = 0; nn < 256; nn += 4) {
        int n = n0 + nn;
        float qf[4][4], pf[4][4];
#pragma unroll
        for (int i = 0; i < 4; i++) {
            ushort4 u = *(const ushort4*)(qkv + qch[i] + n);
            qf[i][0] = u2f(u.x); qf[i][1] = u2f(u.y); qf[i][2] = u2f(u.z); qf[i][3] = u2f(u.w);
            ushort4 v = *(const ushort4*)(qkv + kch[i] + n);
            pf[i][0] = __expf(u2f(v.x)) * ze[i];
            pf[i][1] = __expf(u2f(v.y)) * ze[i];
            pf[i][2] = __expf(u2f(v.z)) * ze[i];
            pf[i][3] = __expf(u2f(v.w)) * ze[i];
        }
#pragma unroll
        for (int di = 0; di < 4; di++)
#pragma unroll
            for (int j = 0; j < 4; j++)
#pragma unroll
                for (int ei = 0; ei < 4; ei++)
                    acc[di][ei] += qf[di][j] * pf[ei][j];
    }
    float* wp = wts + (size_t)bh * 1024;
#pragma unroll
    for (int di = 0; di < 4; di++)
#pragma unroll
        for (int ei = 0; ei < 4; ei++)
            atomicAdd(&wp[(d0 + di) * 32 + e0 + ei], acc[di][ei]);
}

// ---- attnout: block = one image row; stage 64KB NHWC row in swizzled LDS, store dense ----
// grid (256, nb)
__global__ __launch_bounds__(256, 2) void k_attnout(
    const unsigned short* __restrict__ qkv, const float* __restrict__ wts,
    unsigned short* __restrict__ at2, int b0, int nb)
{
    const int tx = threadIdx.x, y = blockIdx.x, bl = blockIdx.y, b = b0 + bl;
    __shared__ short os[256 * 128];   // 65536 B, per-row XOR-swizzled (16B units)
    const unsigned short* vb = qkv + ((size_t)(2 * nb + bl) * CMID) * NPIX + (size_t)y * WW;
    const float* Wb = wts + (size_t)b * 4096;

#pragma unroll
    for (int h = 0; h < 4; h++) {
        float a0[32];
#pragma unroll
        for (int e = 0; e < 32; e++) a0[e] = 0.f;
        for (int d = 0; d < 32; d++) {
            float v0 = u2f(vb[(size_t)(h * 32 + d) * NPIX + tx]);
            const float4* w4 = (const float4*)(Wb + h * 1024 + d * 32);
#pragma unroll
            for (int e4 = 0; e4 < 8; e4++) {
                float4 w = w4[e4];
                a0[e4 * 4 + 0] += w.x * v0;
                a0[e4 * 4 + 1] += w.y * v0;
                a0[e4 * 4 + 2] += w.z * v0;
                a0[e4 * 4 + 3] += w.w * v0;
            }
        }
#pragma unroll
        for (int i = 0; i < 4; i++) {
            uint4 v = make_uint4(pk2(a0[i*8+0], a0[i*8+1]), pk2(a0[i*8+2], a0[i*8+3]),
                                 pk2(a0[i*8+4], a0[i*8+5]), pk2(a0[i*8+6], a0[i*8+7]));
            int inner = (h * 4 + i) ^ (tx & 15);
            *(uint4*)((char*)os + tx * 256 + inner * 16) = v;
        }
    }
    __syncthreads();
    unsigned short* orow = at2 + ((size_t)(bl * PW + 1 + y) * PW + 1) * 128;
#pragma unroll
    for (int p = 0; p < 16; p++) {
        int off = p * 4096 + tx * 16;
        int pxr = off >> 8;
        int inner = (off & 255) >> 4;
        uint4 v = *(const uint4*)((char*)os + pxr * 256 + ((inner ^ (pxr & 15)) << 4));
        *(uint4*)((char*)orow + off) = v;
    }
}

// ---- zero at2 borders ----
__global__ __launch_bounds__(256) void k_bord(unsigned short* __restrict__ at2) {
    const int row = blockIdx.x, bl = blockIdx.y, tx = threadIdx.x;
    unsigned int* rp = (unsigned int*)(at2 + ((size_t)(bl * PW + row) * PW) * 128);
    if (row == 0 || row == PW - 1) {
        for (int i = tx; i < PW * 64; i += 256) rp[i] = 0u;
    } else {
        if (tx < 64) rp[tx] = 0u;
        else if (tx < 128) rp[(size_t)(PW - 1) * 64 + tx - 64] = 0u;
    }
}

// ---- conv2: implicit GEMM from NHWC at2; contiguous 512B store runs ----
// grid: 2*256*nb
__global__ __launch_bounds__(256, 3) void k_conv2(
    const unsigned short* __restrict__ at2, const short* __restrict__ w2t,
    const float* __restrict__ b2, float* __restrict__ out, int b0, int nb)
{
    const int bid = blockIdx.x;
    const int chunk = bid & 1;
    const int y   = (bid >> 1) & 255;
    const int bl  = bid >> 9;
    const int px0 = chunk * 128;
    const int bb  = b0 + bl;
    const int tx  = threadIdx.x;
    const int wv  = tx >> 6, l = tx & 63;
    const int lhi = l >> 4, llo = l & 15;

    __shared__ short xs[3 * 132 * 32];   // 25344 B
    __shared__ float osf[32][132];       // 16896 B

    float bias[2][4];
#pragma unroll
    for (int m = 0; m < 2; m++)
#pragma unroll
        for (int r = 0; r < 4; r++)
            bias[m][r] = b2[m * 16 + lhi * 4 + r];

    f32x4 acc[2][2];
#pragma unroll
    for (int t = 0; t < 2; t++)
#pragma unroll
        for (int m = 0; m < 2; m++) acc[t][m] = (f32x4){0.f, 0.f, 0.f, 0.f};

    for (int cc = 0; cc < 4; cc++) {
        __syncthreads();
        if (wv < 3) {
            const char* src = (const char*)at2 +
                (((size_t)(bl * PW) + y + wv) * PW + px0) * 256 + cc * 64 +
                (size_t)(l >> 2) * 256 + (size_t)(l & 3) * 16;
            char* dst = (char*)xs + wv * 8448;
#pragma unroll
            for (int q = 0; q < 8; q++) gload16(src + (size_t)q * 4096, dst + q * 1024);
            if (l < 8) gload16(src + (size_t)8 * 4096, dst + 8192);
        }
        __syncthreads();

        short8 a[2], an[2];
#pragma unroll
        for (int m = 0; m < 2; m++)
            an[m] = *(const short8*)(w2t + ((size_t)(cc * 4 + lhi) * 32 + m * 16 + llo) * 8);
#pragma unroll
        for (int tap = 0; tap < 9; tap++) {
            const int dy = tap / 3, dx = tap % 3;
#pragma unroll
            for (int m = 0; m < 2; m++) a[m] = an[m];
            if (tap < 8) {
#pragma unroll
                for (int m = 0; m < 2; m++)
                    an[m] = *(const short8*)(w2t +
                        ((size_t)((tap + 1) * 16 + cc * 4 + lhi) * 32 + m * 16 + llo) * 8);
            }
#pragma unroll
            for (int t = 0; t < 2; t++) {
                short8 bfr = *(const short8*)&xs[((dy * 132 + wv * 32 + t * 16 + llo + dx) << 5) + (lhi << 3)];
#pragma unroll
                for (int m = 0; m < 2; m++)
                    acc[t][m] = __builtin_amdgcn_mfma_f32_16x16x32_bf16(a[m], bfr, acc[t][m], 0, 0, 0);
            }
        }
    }

    // LDS-staged epilogue: 32 lanes x 16B = 512B contiguous per channel per instr
#pragma unroll
    for (int t = 0; t < 2; t++)
#pragma unroll
        for (int m = 0; m < 2; m++)
#pragma unroll
            for (int r = 0; r < 4; r++)
                osf[m * 16 + lhi * 4 + r][wv * 32 + t * 16 + llo] = acc[t][m][r] + bias[m][r];
    __syncthreads();
#pragma unroll
    for (int p = 0; p < 4; p++) {
        int chl = p * 8 + (tx >> 5);
        float4 v = *(const float4*)&osf[chl][(tx & 31) * 4];
        *(float4*)(out + ((size_t)bb * COUT + chl) * NPIX + y * WW + px0 + (tx & 31) * 4) = v;
    }
}

extern "C" void kernel_launch(void* const* d_in, const int* in_sizes, int n_in,
                              void* d_out, int out_size, void* d_ws, size_t ws_size,
                              hipStream_t stream) {
    const float* x  = (const float*)d_in[0];
    const float* w1 = (const float*)d_in[1];
    const float* b1 = (const float*)d_in[2];
    const float* w2 = (const float*)d_in[3];
    const float* b2 = (const float*)d_in[4];
    float* out = (float*)d_out;

    char* ws = (char*)d_ws;
    float* rinv = (float*)(ws);
    float* wts  = (float*)(ws + 4096);
    short* w1t  = (short*)(ws + 69632);
    short* w2t  = (short*)(ws + 290816);
    const size_t OFF_XT = 1048576;

    int nb = 4;
    {
        size_t xt_sz  = (size_t)nb * PW * PW * 64;
        size_t total  = OFF_XT + xt_sz + (size_t)3 * nb * CMID * NPIX * 2;
        if (ws_size < total) nb = 1;
    }
    const size_t xt_sz   = (size_t)nb * PW * PW * 64;
    const size_t qkv_off = OFF_XT + xt_sz;
    const size_t q_sz    = (size_t)nb * CMID * NPIX * 2;
    const size_t at2_off = qkv_off + q_sz - (size_t)nb * PW * PW * 256;

    unsigned short* xt  = (unsigned short*)(ws + OFF_XT);
    unsigned short* qkv = (unsigned short*)(ws + qkv_off);
    unsigned short* at2 = (unsigned short*)(ws + at2_off);

    k_zero<<<dim3(64), 256, 0, stream>>>(wts, 16 * 1024);
    k_w1t <<<dim3(9),  256, 0, stream>>>(w1, w1t);
    k_w2t <<<dim3(9),  256, 0, stream>>>(w2, w2t);

    for (int b0 = 0; b0 < B_; b0 += nb) {
        k_xt     <<<dim3(PW, nb),      256, 0, stream>>>(x, xt, b0);
        k_conv1  <<<dim3(2 * HH * nb), 256, 0, stream>>>(xt, w1t, b1, qkv, nb);
        k_stats  <<<dim3(nb * CMID),   256, 0, stream>>>(qkv, rinv, b0, nb);
        k_weights<<<dim3(64, nb * 4),  256, 0, stream>>>(qkv, rinv, wts, b0, nb);
        k_bord   <<<dim3(PW, nb),      256, 0, stream>>>(at2);
        k_attnout<<<dim3(HH, nb),      256, 0, stream>>>(qkv, wts, at2, b0, nb);
        k_conv2  <<<dim3(2 * HH * nb), 256, 0, stream>>>(at2, w2t, b2, out, b0, nb);
    }
}

// Round 8
// 282.102 us; speedup vs baseline: 11.6805x; 1.7268x over previous
//
#include <hip/hip_runtime.h>
#include <hip/hip_bf16.h>

typedef __hip_bfloat16 bf16;
typedef __attribute__((ext_vector_type(8))) short short8;
typedef __attribute__((ext_vector_type(4))) float f32x4;
typedef __attribute__((ext_vector_type(16))) float f32x16;

#define B_    4
#define CIN   32
#define HH    256
#define WW    256
#define C1    384
#define NPIX  65536
#define CMID  128
#define COUT  32
#define PW    258   // padded spatial width
#define NCH   64    // n-chunks for weights GEMM

static __device__ __forceinline__ float u2f(unsigned short u) {
    unsigned int x = ((unsigned int)u) << 16;
    return __uint_as_float(x);
}
static __device__ __forceinline__ unsigned short f2u(float f) {
    bf16 h = __float2bfloat16(f);
    return __builtin_bit_cast(unsigned short, h);
}
static __device__ __forceinline__ unsigned int pk2(float lo, float hi) {
    return (unsigned int)f2u(lo) | ((unsigned int)f2u(hi) << 16);
}
// async global->LDS, 16B per active lane; dst wave-uniform base (HW adds lane*16)
static __device__ __forceinline__ void gload16(const void* src, void* dst) {
    __builtin_amdgcn_global_load_lds(
        (const __attribute__((address_space(1))) void*)src,
        (__attribute__((address_space(3))) void*)dst, 16, 0, 0);
}

// ---- w1(384,32,3,3) fp32 -> w1t[tap][cihi4][co384][8] bf16 ----
__global__ __launch_bounds__(256) void k_w1t(const float* __restrict__ w1, short* __restrict__ w1t) {
    const int tap = blockIdx.x;
    for (int i = threadIdx.x; i < 384 * 32; i += 256) {
        int co = i >> 5, cij = i & 31;
        w1t[((size_t)(tap * 4 + (cij >> 3)) * 384 + co) * 8 + (cij & 7)] =
            (short)f2u(w1[(size_t)i * 9 + tap]);
    }
}
// ---- w2(32,128,3,3) fp32 -> w2t[tap][cihi16][co32][8] bf16 ----
__global__ __launch_bounds__(256) void k_w2t(const float* __restrict__ w2, short* __restrict__ w2t) {
    const int tap = blockIdx.x;
    for (int i = threadIdx.x; i < 32 * 128; i += 256) {
        int co = i >> 7, cij = i & 127;
        w2t[((size_t)(tap * 16 + (cij >> 3)) * 32 + co) * 8 + (cij & 7)] =
            (short)f2u(w2[(size_t)i * 9 + tap]);
    }
}

// ---- x(b,32,256,256) fp32 -> xt[bl][row][col][32] bf16, zero-padded borders ----
__global__ __launch_bounds__(256) void k_xt(const float* __restrict__ x,
                                            unsigned short* __restrict__ xt, int b0) {
    const int row = blockIdx.x, bl = blockIdx.y, b = b0 + bl;
    const int tx = threadIdx.x;
    unsigned int* rp = (unsigned int*)(xt + ((size_t)(bl * PW + row) * PW) * 32);
    if (row == 0 || row == PW - 1) {
        for (int i = tx; i < PW * 16; i += 256) rp[i] = 0u;
        return;
    }
    if (tx < 2) {
        unsigned int* cp = rp + (size_t)(tx * (PW - 1)) * 16;
#pragma unroll
        for (int i = 0; i < 16; i++) cp[i] = 0u;
    }
    const int col = tx + 1;
    const size_t px = (size_t)(row - 1) * WW + tx;
    unsigned int pk[16];
#pragma unroll
    for (int c2 = 0; c2 < 16; c2++) {
        float v0 = x[((size_t)b * CIN + 2 * c2) * NPIX + px];
        float v1 = x[((size_t)b * CIN + 2 * c2 + 1) * NPIX + px];
        pk[c2] = pk2(v0, v1);
    }
    uint4* dst = (uint4*)(rp + (size_t)col * 16);
#pragma unroll
    for (int q = 0; q < 4; q++)
        dst[q] = make_uint4(pk[q * 4], pk[q * 4 + 1], pk[q * 4 + 2], pk[q * 4 + 3]);
}

// ---- conv1: merged-co implicit GEMM. Block = (y, 128px chunk), all 384 co in 6 groups ----
__global__ __launch_bounds__(256, 2) void k_conv1(
    const unsigned short* __restrict__ xt, const short* __restrict__ w1t,
    const float* __restrict__ b1, unsigned short* __restrict__ qkv, int nb)
{
    const int bid = blockIdx.x;
    const int chunk = bid & 1;
    const int y   = (bid >> 1) & 255;
    const int bl  = bid >> 9;
    const int px0 = chunk * 128;
    const int tx  = threadIdx.x;
    const int wv  = tx >> 6, l = tx & 63;
    const int lhi = l >> 4, llo = l & 15;

    __shared__ short xs[3 * 132 * 32];
    __shared__ short wt[9][4][64][8];
    __shared__ short os[64][136];

    if (wv < 3) {
        const char* src = (const char*)xt +
            (((size_t)(bl * PW) + y + wv) * PW + px0) * 64 + (size_t)l * 16;
        char* dst = (char*)xs + wv * 8448;
#pragma unroll
        for (int q = 0; q < 8; q++) gload16(src + q * 1024, dst + q * 1024);
        if (l < 8) gload16(src + 8192, dst + 8192);
    }
#pragma unroll
    for (int i = 0; i < 9; i++) {
        int s = wv * 9 + i;
        int tap = s >> 2, ch = s & 3;
        const char* src = (const char*)w1t + ((size_t)(tap * 4 + ch) * 384) * 16 + (size_t)l * 16;
        gload16(src, (char*)&wt[tap][ch][0][0]);
    }
    __syncthreads();

    for (int cog = 0; cog < 6; cog++) {
        const int co0 = cog * 64;
        float bias[4][4];
#pragma unroll
        for (int mc = 0; mc < 4; mc++)
#pragma unroll
            for (int r = 0; r < 4; r++)
                bias[mc][r] = b1[co0 + mc * 16 + lhi * 4 + r];

        f32x4 acc[2][4];
#pragma unroll
        for (int t = 0; t < 2; t++)
#pragma unroll
            for (int mc = 0; mc < 4; mc++) acc[t][mc] = (f32x4){0.f, 0.f, 0.f, 0.f};

#pragma unroll
        for (int tap = 0; tap < 9; tap++) {
            const int dy = tap / 3, dx = tap % 3;
            short8 a[4];
#pragma unroll
            for (int mc = 0; mc < 4; mc++)
                a[mc] = *(const short8*)&wt[tap][lhi][mc * 16 + llo][0];
#pragma unroll
            for (int t = 0; t < 2; t++) {
                short8 bfr = *(const short8*)&xs[((dy * 132 + wv * 32 + t * 16 + llo + dx) << 5) + (lhi << 3)];
#pragma unroll
                for (int mc = 0; mc < 4; mc++)
                    acc[t][mc] = __builtin_amdgcn_mfma_f32_16x16x32_bf16(a[mc], bfr, acc[t][mc], 0, 0, 0);
            }
        }
        __syncthreads();

#pragma unroll
        for (int t = 0; t < 2; t++)
#pragma unroll
            for (int mc = 0; mc < 4; mc++)
#pragma unroll
                for (int r = 0; r < 4; r++)
                    os[mc * 16 + lhi * 4 + r][wv * 32 + t * 16 + llo] =
                        (short)f2u(acc[t][mc][r] + bias[mc][r]);

        if (cog < 5) {
#pragma unroll
            for (int i = 0; i < 9; i++) {
                int s = wv * 9 + i;
                int tap = s >> 2, ch = s & 3;
                const char* src = (const char*)w1t +
                    ((size_t)(tap * 4 + ch) * 384 + co0 + 64) * 16 + (size_t)l * 16;
                gload16(src, (char*)&wt[tap][ch][0][0]);
            }
        }
        __syncthreads();

#pragma unroll
        for (int p = 0; p < 4; p++) {
            int chl = p * 16 + (tx >> 4);
            int c = co0 + chl;
            int comp = c >> 7, chn = c & 127;
            uint4 v = *(const uint4*)&os[chl][(tx & 15) * 8];
            *(uint4*)(qkv + ((size_t)(comp * nb + bl) * CMID + chn) * NPIX
                      + y * WW + px0 + (tx & 15) * 8) = v;
        }
    }
}

// ---- weights GEMM: partial W'[d,e] = sum_n q[d,n]*exp(k[e,n]) via mfma 32x32x16,
//      plus partial S[e] = sum_n exp(k[e,n]).  grid (NCH, nb*4) ----
__global__ __launch_bounds__(256) void k_weights(
    const unsigned short* __restrict__ qkv, float* __restrict__ pw,
    float* __restrict__ ps, int nb)
{
    const int c  = blockIdx.x;
    const int bh = blockIdx.y;           // bl*4+h
    const int bl = bh >> 2, h = bh & 3;
    const int tx = threadIdx.x;
    const int wv = tx >> 6, l = tx & 63;
    const int col = l & 31;              // d-row for A, e-col for B
    const int kg  = l >> 5;

    const unsigned short* qb = qkv + ((size_t)bl * CMID + h * 32 + col) * NPIX;
    const unsigned short* kb = qkv + ((size_t)(nb + bl) * CMID + h * 32 + col) * NPIX;
    const int n0 = c * 1024 + wv * 256 + kg * 8;

    f32x16 acc;
#pragma unroll
    for (int r = 0; r < 16; r++) acc[r] = 0.f;
    float se = 0.f;

#pragma unroll 4
    for (int s = 0; s < 16; s++) {
        const int n = n0 + s * 16;
        short8 qf = *(const short8*)(qb + n);
        short8 kf = *(const short8*)(kb + n);
        float ef[8];
#pragma unroll
        for (int j = 0; j < 8; j++) {
            ef[j] = __expf(u2f((unsigned short)kf[j]));
            se += ef[j];
        }
        short8 pf;
#pragma unroll
        for (int j = 0; j < 8; j++) pf[j] = (short)f2u(ef[j]);
        acc = __builtin_amdgcn_mfma_f32_32x32x16_bf16(qf, pf, acc, 0, 0, 0);
    }

    __shared__ float red[4][1024];
    __shared__ float sred[4][64];
#pragma unroll
    for (int r = 0; r < 16; r++) {
        int row = (r & 3) + 8 * (r >> 2) + 4 * kg;
        red[wv][row * 32 + col] = acc[r];
    }
    sred[wv][l] = se;
    __syncthreads();

    float* pwp = pw + ((size_t)bh * NCH + c) * 1024;
#pragma unroll
    for (int j = 0; j < 4; j++) {
        int i = tx + 256 * j;
        pwp[i] = red[0][i] + red[1][i] + red[2][i] + red[3][i];
    }
    if (tx < 32) {
        float s = 0.f;
#pragma unroll
        for (int w = 0; w < 4; w++) s += sred[w][tx] + sred[w][tx + 32];
        ps[((size_t)bh * NCH + c) * 32 + tx] = s;
    }
}

// ---- reduce partials: wts[bh][d*32+e] = (sum_c pw) / (sum_c S[e]).  grid (nb*4, 4) ----
__global__ __launch_bounds__(256) void k_wred(
    const float* __restrict__ pw, const float* __restrict__ ps,
    float* __restrict__ wts, int b0)
{
    const int bh = blockIdx.x;
    const int jq = blockIdx.y;
    const int tx = threadIdx.x;
    __shared__ float rinvs[32];
    if (tx < 32) {
        float s = 0.f;
        for (int c = 0; c < NCH; c++) s += ps[((size_t)bh * NCH + c) * 32 + tx];
        rinvs[tx] = 1.f / s;
    }
    __syncthreads();
    const int i = jq * 256 + tx;
    const float* pwp = pw + (size_t)bh * NCH * 1024;
    float s = 0.f;
    for (int c = 0; c < NCH; c++) s += pwp[c * 1024 + i];
    wts[(size_t)(b0 * 4 + bh) * 1024 + i] = s * rinvs[i & 31];
}

// ---- attnout: block = one image row; stage 64KB NHWC row in swizzled LDS, store dense ----
__global__ __launch_bounds__(256, 2) void k_attnout(
    const unsigned short* __restrict__ qkv, const float* __restrict__ wts,
    unsigned short* __restrict__ at2, int b0, int nb)
{
    const int tx = threadIdx.x, y = blockIdx.x, bl = blockIdx.y, b = b0 + bl;
    __shared__ short os[256 * 128];
    const unsigned short* vb = qkv + ((size_t)(2 * nb + bl) * CMID) * NPIX + (size_t)y * WW;
    const float* Wb = wts + (size_t)b * 4096;

#pragma unroll
    for (int h = 0; h < 4; h++) {
        float a0[32];
#pragma unroll
        for (int e = 0; e < 32; e++) a0[e] = 0.f;
        for (int d = 0; d < 32; d++) {
            float v0 = u2f(vb[(size_t)(h * 32 + d) * NPIX + tx]);
            const float4* w4 = (const float4*)(Wb + h * 1024 + d * 32);
#pragma unroll
            for (int e4 = 0; e4 < 8; e4++) {
                float4 w = w4[e4];
                a0[e4 * 4 + 0] += w.x * v0;
                a0[e4 * 4 + 1] += w.y * v0;
                a0[e4 * 4 + 2] += w.z * v0;
                a0[e4 * 4 + 3] += w.w * v0;
            }
        }
#pragma unroll
        for (int i = 0; i < 4; i++) {
            uint4 v = make_uint4(pk2(a0[i*8+0], a0[i*8+1]), pk2(a0[i*8+2], a0[i*8+3]),
                                 pk2(a0[i*8+4], a0[i*8+5]), pk2(a0[i*8+6], a0[i*8+7]));
            int inner = (h * 4 + i) ^ (tx & 15);
            *(uint4*)((char*)os + tx * 256 + inner * 16) = v;
        }
    }
    __syncthreads();
    unsigned short* orow = at2 + ((size_t)(bl * PW + 1 + y) * PW + 1) * 128;
#pragma unroll
    for (int p = 0; p < 16; p++) {
        int off = p * 4096 + tx * 16;
        int pxr = off >> 8;
        int inner = (off & 255) >> 4;
        uint4 v = *(const uint4*)((char*)os + pxr * 256 + ((inner ^ (pxr & 15)) << 4));
        *(uint4*)((char*)orow + off) = v;
    }
}

// ---- zero at2 borders ----
__global__ __launch_bounds__(256) void k_bord(unsigned short* __restrict__ at2) {
    const int row = blockIdx.x, bl = blockIdx.y, tx = threadIdx.x;
    unsigned int* rp = (unsigned int*)(at2 + ((size_t)(bl * PW + row) * PW) * 128);
    if (row == 0 || row == PW - 1) {
        for (int i = tx; i < PW * 64; i += 256) rp[i] = 0u;
    } else {
        if (tx < 64) rp[tx] = 0u;
        else if (tx < 128) rp[(size_t)(PW - 1) * 64 + tx - 64] = 0u;
    }
}

// ---- conv2: implicit GEMM from NHWC at2; contiguous 512B store runs ----
__global__ __launch_bounds__(256, 3) void k_conv2(
    const unsigned short* __restrict__ at2, const short* __restrict__ w2t,
    const float* __restrict__ b2, float* __restrict__ out, int b0, int nb)
{
    const int bid = blockIdx.x;
    const int chunk = bid & 1;
    const int y   = (bid >> 1) & 255;
    const int bl  = bid >> 9;
    const int px0 = chunk * 128;
    const int bb  = b0 + bl;
    const int tx  = threadIdx.x;
    const int wv  = tx >> 6, l = tx & 63;
    const int lhi = l >> 4, llo = l & 15;

    __shared__ short xs[3 * 132 * 32];
    __shared__ float osf[32][132];

    float bias[2][4];
#pragma unroll
    for (int m = 0; m < 2; m++)
#pragma unroll
        for (int r = 0; r < 4; r++)
            bias[m][r] = b2[m * 16 + lhi * 4 + r];

    f32x4 acc[2][2];
#pragma unroll
    for (int t = 0; t < 2; t++)
#pragma unroll
        for (int m = 0; m < 2; m++) acc[t][m] = (f32x4){0.f, 0.f, 0.f, 0.f};

    for (int cc = 0; cc < 4; cc++) {
        __syncthreads();
        if (wv < 3) {
            const char* src = (const char*)at2 +
                (((size_t)(bl * PW) + y + wv) * PW + px0) * 256 + cc * 64 +
                (size_t)(l >> 2) * 256 + (size_t)(l & 3) * 16;
            char* dst = (char*)xs + wv * 8448;
#pragma unroll
            for (int q = 0; q < 8; q++) gload16(src + (size_t)q * 4096, dst + q * 1024);
            if (l < 8) gload16(src + (size_t)8 * 4096, dst + 8192);
        }
        __syncthreads();

        short8 a[2], an[2];
#pragma unroll
        for (int m = 0; m < 2; m++)
            an[m] = *(const short8*)(w2t + ((size_t)(cc * 4 + lhi) * 32 + m * 16 + llo) * 8);
#pragma unroll
        for (int tap = 0; tap < 9; tap++) {
            const int dy = tap / 3, dx = tap % 3;
#pragma unroll
            for (int m = 0; m < 2; m++) a[m] = an[m];
            if (tap < 8) {
#pragma unroll
                for (int m = 0; m < 2; m++)
                    an[m] = *(const short8*)(w2t +
                        ((size_t)((tap + 1) * 16 + cc * 4 + lhi) * 32 + m * 16 + llo) * 8);
            }
#pragma unroll
            for (int t = 0; t < 2; t++) {
                short8 bfr = *(const short8*)&xs[((dy * 132 + wv * 32 + t * 16 + llo + dx) << 5) + (lhi << 3)];
#pragma unroll
                for (int m = 0; m < 2; m++)
                    acc[t][m] = __builtin_amdgcn_mfma_f32_16x16x32_bf16(a[m], bfr, acc[t][m], 0, 0, 0);
            }
        }
    }

#pragma unroll
    for (int t = 0; t < 2; t++)
#pragma unroll
        for (int m = 0; m < 2; m++)
#pragma unroll
            for (int r = 0; r < 4; r++)
                osf[m * 16 + lhi * 4 + r][wv * 32 + t * 16 + llo] = acc[t][m][r] + bias[m][r];
    __syncthreads();
#pragma unroll
    for (int p = 0; p < 4; p++) {
        int chl = p * 8 + (tx >> 5);
        float4 v = *(const float4*)&osf[chl][(tx & 31) * 4];
        *(float4*)(out + ((size_t)bb * COUT + chl) * NPIX + y * WW + px0 + (tx & 31) * 4) = v;
    }
}

extern "C" void kernel_launch(void* const* d_in, const int* in_sizes, int n_in,
                              void* d_out, int out_size, void* d_ws, size_t ws_size,
                              hipStream_t stream) {
    const float* x  = (const float*)d_in[0];
    const float* w1 = (const float*)d_in[1];
    const float* b1 = (const float*)d_in[2];
    const float* w2 = (const float*)d_in[3];
    const float* b2 = (const float*)d_in[4];
    float* out = (float*)d_out;

    char* ws = (char*)d_ws;
    float* wts  = (float*)(ws + 4096);     // 16*1024 f = 64 KB
    short* w1t  = (short*)(ws + 69632);
    short* w2t  = (short*)(ws + 290816);
    const size_t OFF_XT = 1048576;

    int nb = 4;
    {
        size_t xt_sz  = (size_t)nb * PW * PW * 64;
        size_t total  = OFF_XT + xt_sz + (size_t)3 * nb * CMID * NPIX * 2;
        if (ws_size < total) nb = 1;
    }
    const size_t xt_sz   = (size_t)nb * PW * PW * 64;
    const size_t qkv_off = OFF_XT + xt_sz;
    const size_t q_sz    = (size_t)nb * CMID * NPIX * 2;
    const size_t at2_off = qkv_off + q_sz - (size_t)nb * PW * PW * 256;

    unsigned short* xt  = (unsigned short*)(ws + OFF_XT);
    unsigned short* qkv = (unsigned short*)(ws + qkv_off);
    unsigned short* at2 = (unsigned short*)(ws + at2_off);
    // weights partials overlay the (dead-after-conv1) xt region
    float* pw = (float*)(ws + OFF_XT);                                   // nb*4*NCH*4KB
    float* ps = (float*)(ws + OFF_XT + (size_t)nb * 4 * NCH * 1024 * 4); // nb*4*NCH*128B

    k_w1t<<<dim3(9), 256, 0, stream>>>(w1, w1t);
    k_w2t<<<dim3(9), 256, 0, stream>>>(w2, w2t);

    for (int b0 = 0; b0 < B_; b0 += nb) {
        k_xt     <<<dim3(PW, nb),       256, 0, stream>>>(x, xt, b0);
        k_conv1  <<<dim3(2 * HH * nb),  256, 0, stream>>>(xt, w1t, b1, qkv, nb);
        k_weights<<<dim3(NCH, nb * 4),  256, 0, stream>>>(qkv, pw, ps, nb);
        k_wred   <<<dim3(nb * 4, 4),    256, 0, stream>>>(pw, ps, wts, b0);
        k_bord   <<<dim3(PW, nb),       256, 0, stream>>>(at2);
        k_attnout<<<dim3(HH, nb),       256, 0, stream>>>(qkv, wts, at2, b0, nb);
        k_conv2  <<<dim3(2 * HH * nb),  256, 0, stream>>>(at2, w2t, b2, out, b0, nb);
    }
}

// Round 9
// 236.391 us; speedup vs baseline: 13.9392x; 1.1934x over previous
//
#include <hip/hip_runtime.h>
#include <hip/hip_bf16.h>

typedef __hip_bfloat16 bf16;
typedef __attribute__((ext_vector_type(8))) short short8;
typedef __attribute__((ext_vector_type(4))) float f32x4;
typedef __attribute__((ext_vector_type(16))) float f32x16;

#define B_    4
#define CIN   32
#define HH    256
#define WW    256
#define C1    384
#define NPIX  65536
#define CMID  128
#define COUT  32
#define PW    258
#define NCH   64

static __device__ __forceinline__ float u2f(unsigned short u) {
    unsigned int x = ((unsigned int)u) << 16;
    return __uint_as_float(x);
}
static __device__ __forceinline__ unsigned short f2u(float f) {
    bf16 h = __float2bfloat16(f);
    return __builtin_bit_cast(unsigned short, h);
}
static __device__ __forceinline__ unsigned int pk2(float lo, float hi) {
    return (unsigned int)f2u(lo) | ((unsigned int)f2u(hi) << 16);
}
static __device__ __forceinline__ void gload16(const void* src, void* dst) {
    __builtin_amdgcn_global_load_lds(
        (const __attribute__((address_space(1))) void*)src,
        (__attribute__((address_space(3))) void*)dst, 16, 0, 0);
}

// ---- w1(384,32,3,3) fp32 -> w1t[tap][cihi4][co384][8] bf16 ----
__global__ __launch_bounds__(256) void k_w1t(const float* __restrict__ w1, short* __restrict__ w1t) {
    const int tap = blockIdx.x;
    for (int i = threadIdx.x; i < 384 * 32; i += 256) {
        int co = i >> 5, cij = i & 31;
        w1t[((size_t)(tap * 4 + (cij >> 3)) * 384 + co) * 8 + (cij & 7)] =
            (short)f2u(w1[(size_t)i * 9 + tap]);
    }
}
// ---- w2(32,128,3,3) fp32 -> w2t[tap][cihi16][co32][8] bf16 ----
__global__ __launch_bounds__(256) void k_w2t(const float* __restrict__ w2, short* __restrict__ w2t) {
    const int tap = blockIdx.x;
    for (int i = threadIdx.x; i < 32 * 128; i += 256) {
        int co = i >> 7, cij = i & 127;
        w2t[((size_t)(tap * 16 + (cij >> 3)) * 32 + co) * 8 + (cij & 7)] =
            (short)f2u(w2[(size_t)i * 9 + tap]);
    }
}

// ---- x -> xt2[bl][row][cihi4][col PW][8ch] bf16, zero-padded ----
__global__ __launch_bounds__(256) void k_xt2(const float* __restrict__ x,
                                             unsigned short* __restrict__ xt2, int b0) {
    const int row = blockIdx.x, bl = blockIdx.y, b = b0 + bl;
    const int tx = threadIdx.x;
    unsigned short* rbase = xt2 + (size_t)(bl * PW + row) * 4 * PW * 8;
    const uint4 z = make_uint4(0u, 0u, 0u, 0u);
    if (row == 0 || row == PW - 1) {
        for (int i = tx; i < 4 * PW; i += 256) ((uint4*)rbase)[i] = z;
        return;
    }
    if (tx < 2) {
        int c = tx ? (PW - 1) : 0;
#pragma unroll
        for (int ch = 0; ch < 4; ch++)
            *(uint4*)(rbase + ((size_t)ch * PW + c) * 8) = z;
    }
    const int col = tx + 1;
    const size_t px = (size_t)(row - 1) * WW + tx;
    unsigned int pk[16];
#pragma unroll
    for (int c2 = 0; c2 < 16; c2++) {
        float v0 = x[((size_t)b * CIN + 2 * c2) * NPIX + px];
        float v1 = x[((size_t)b * CIN + 2 * c2 + 1) * NPIX + px];
        pk[c2] = pk2(v0, v1);
    }
#pragma unroll
    for (int ch = 0; ch < 4; ch++)
        *(uint4*)(rbase + ((size_t)ch * PW + col) * 8) =
            make_uint4(pk[ch * 4], pk[ch * 4 + 1], pk[ch * 4 + 2], pk[ch * 4 + 3]);
}

// ---- conv1: block = (128px chunk, y, bl); all 384 co in 6 groups.
//      q,k -> channel-major qkv; v -> NHWC vt (2 planes of 64ch) ----
__global__ __launch_bounds__(256, 2) void k_conv1(
    const unsigned short* __restrict__ xt2, const short* __restrict__ w1t,
    const float* __restrict__ b1, unsigned short* __restrict__ qkv,
    unsigned short* __restrict__ vt, int nb)
{
    const int bid = blockIdx.x;
    const int chunk = bid & 1;
    const int y   = (bid >> 1) & 255;
    const int bl  = bid >> 9;
    const int px0 = chunk * 128;
    const int tx  = threadIdx.x;
    const int wv  = tx >> 6, l = tx & 63;
    const int lhi = l >> 4, llo = l & 15;

    __shared__ short xs[12 * 132 * 8];      // [(r*4+ch)][col132][8]  25344 B
    __shared__ short wt[9][4][64][8];       // 36864 B
    __shared__ union { short os[64][136]; short ost[128][66]; } ou;  // 17408 B

    // stage x patch: 12 (row,cihi) segs of 130 cols (2080 B each)
#pragma unroll
    for (int i = 0; i < 3; i++) {
        int p = wv * 3 + i;
        int r = p >> 2, ch = p & 3;
        const char* src = (const char*)xt2 +
            (((size_t)(bl * PW) + y + r) * 4 + ch) * (PW * 16) + (size_t)px0 * 16 + (size_t)l * 16;
        char* dst = (char*)xs + p * 2112;
        gload16(src, dst);
        gload16(src + 1024, dst + 1024);
        if (l < 2) gload16(src + 2048, dst + 2048);
    }
    // stage weight tile cog0
#pragma unroll
    for (int i = 0; i < 9; i++) {
        int s = wv * 9 + i;
        int tap = s >> 2, ch = s & 3;
        const char* src = (const char*)w1t + ((size_t)(tap * 4 + ch) * 384) * 16 + (size_t)l * 16;
        gload16(src, (char*)&wt[tap][ch][0][0]);
    }
    __syncthreads();

    for (int cog = 0; cog < 6; cog++) {
        const int co0 = cog * 64;
        float bias[4][4];
#pragma unroll
        for (int mc = 0; mc < 4; mc++)
#pragma unroll
            for (int r = 0; r < 4; r++)
                bias[mc][r] = b1[co0 + mc * 16 + lhi * 4 + r];

        f32x4 acc[2][4];
#pragma unroll
        for (int t = 0; t < 2; t++)
#pragma unroll
            for (int mc = 0; mc < 4; mc++) acc[t][mc] = (f32x4){0.f, 0.f, 0.f, 0.f};

#pragma unroll
        for (int tap = 0; tap < 9; tap++) {
            const int dy = tap / 3, dx = tap % 3;
            short8 a[4];
#pragma unroll
            for (int mc = 0; mc < 4; mc++)
                a[mc] = *(const short8*)&wt[tap][lhi][mc * 16 + llo][0];
#pragma unroll
            for (int t = 0; t < 2; t++) {
                short8 bfr = *(const short8*)&xs[(((dy * 4 + lhi) * 132) + (wv * 32 + t * 16 + llo + dx)) * 8];
#pragma unroll
                for (int mc = 0; mc < 4; mc++)
                    acc[t][mc] = __builtin_amdgcn_mfma_f32_16x16x32_bf16(a[mc], bfr, acc[t][mc], 0, 0, 0);
            }
        }
        __syncthreads();   // wt[cog] reads + previous epilogue reads done

        if (cog < 4) {     // q,k: channel-major staging
#pragma unroll
            for (int t = 0; t < 2; t++)
#pragma unroll
                for (int mc = 0; mc < 4; mc++)
#pragma unroll
                    for (int r = 0; r < 4; r++)
                        ou.os[mc * 16 + lhi * 4 + r][wv * 32 + t * 16 + llo] =
                            (short)f2u(acc[t][mc][r] + bias[mc][r]);
        } else {           // v: transposed [px][ch] staging
#pragma unroll
            for (int t = 0; t < 2; t++)
#pragma unroll
                for (int mc = 0; mc < 4; mc++)
#pragma unroll
                    for (int r = 0; r < 4; r++)
                        ou.ost[wv * 32 + t * 16 + llo][mc * 16 + lhi * 4 + r] =
                            (short)f2u(acc[t][mc][r] + bias[mc][r]);
        }

        if (cog < 5) {
#pragma unroll
            for (int i = 0; i < 9; i++) {
                int s = wv * 9 + i;
                int tap = s >> 2, ch = s & 3;
                const char* src = (const char*)w1t +
                    ((size_t)(tap * 4 + ch) * 384 + co0 + 64) * 16 + (size_t)l * 16;
                gload16(src, (char*)&wt[tap][ch][0][0]);
            }
        }
        __syncthreads();

        if (cog < 4) {
#pragma unroll
            for (int p = 0; p < 4; p++) {
                int chl = p * 16 + (tx >> 4);
                int c = co0 + chl;
                int comp = c >> 7, chn = c & 127;
                uint4 v = *(const uint4*)&ou.os[chl][(tx & 15) * 8];
                *(uint4*)(qkv + ((size_t)(comp * nb + bl) * CMID + chn) * NPIX
                          + y * WW + px0 + (tx & 15) * 8) = v;
            }
        } else {
            const int px = tx >> 1, half = tx & 1;
            const uint4* ls = (const uint4*)&ou.ost[px][half * 32];
            uint4 v0 = ls[0], v1 = ls[1], v2 = ls[2], v3 = ls[3];
            unsigned short* dst = vt + ((size_t)(bl * 2 + (cog - 4)) * NPIX
                                        + y * WW + px0 + px) * 64 + half * 32;
            ((uint4*)dst)[0] = v0; ((uint4*)dst)[1] = v1;
            ((uint4*)dst)[2] = v2; ((uint4*)dst)[3] = v3;
        }
    }
}

// ---- weights GEMM partials (unchanged) ----
__global__ __launch_bounds__(256) void k_weights(
    const unsigned short* __restrict__ qkv, float* __restrict__ pw,
    float* __restrict__ ps, int nb)
{
    const int c  = blockIdx.x;
    const int bh = blockIdx.y;
    const int bl = bh >> 2, h = bh & 3;
    const int tx = threadIdx.x;
    const int wv = tx >> 6, l = tx & 63;
    const int col = l & 31;
    const int kg  = l >> 5;

    const unsigned short* qb = qkv + ((size_t)bl * CMID + h * 32 + col) * NPIX;
    const unsigned short* kb = qkv + ((size_t)(nb + bl) * CMID + h * 32 + col) * NPIX;
    const int n0 = c * 1024 + wv * 256 + kg * 8;

    f32x16 acc;
#pragma unroll
    for (int r = 0; r < 16; r++) acc[r] = 0.f;
    float se = 0.f;

#pragma unroll 4
    for (int s = 0; s < 16; s++) {
        const int n = n0 + s * 16;
        short8 qf = *(const short8*)(qb + n);
        short8 kf = *(const short8*)(kb + n);
        float ef[8];
#pragma unroll
        for (int j = 0; j < 8; j++) {
            ef[j] = __expf(u2f((unsigned short)kf[j]));
            se += ef[j];
        }
        short8 pf;
#pragma unroll
        for (int j = 0; j < 8; j++) pf[j] = (short)f2u(ef[j]);
        acc = __builtin_amdgcn_mfma_f32_32x32x16_bf16(qf, pf, acc, 0, 0, 0);
    }

    __shared__ float red[4][1024];
    __shared__ float sred[4][64];
#pragma unroll
    for (int r = 0; r < 16; r++) {
        int row = (r & 3) + 8 * (r >> 2) + 4 * kg;
        red[wv][row * 32 + col] = acc[r];
    }
    sred[wv][l] = se;
    __syncthreads();

    float* pwp = pw + ((size_t)bh * NCH + c) * 1024;
#pragma unroll
    for (int j = 0; j < 4; j++) {
        int i = tx + 256 * j;
        pwp[i] = red[0][i] + red[1][i] + red[2][i] + red[3][i];
    }
    if (tx < 32) {
        float s = 0.f;
#pragma unroll
        for (int w = 0; w < 4; w++) s += sred[w][tx] + sred[w][tx + 32];
        ps[((size_t)bh * NCH + c) * 32 + tx] = s;
    }
}

// ---- reduce partials (unchanged) ----
__global__ __launch_bounds__(256) void k_wred(
    const float* __restrict__ pw, const float* __restrict__ ps,
    float* __restrict__ wts, int b0)
{
    const int bh = blockIdx.x;
    const int jq = blockIdx.y;
    const int tx = threadIdx.x;
    __shared__ float rinvs[32];
    if (tx < 32) {
        float s = 0.f;
        for (int c = 0; c < NCH; c++) s += ps[((size_t)bh * NCH + c) * 32 + tx];
        rinvs[tx] = 1.f / s;
    }
    __syncthreads();
    const int i = jq * 256 + tx;
    const float* pwp = pw + (size_t)bh * NCH * 1024;
    float s = 0.f;
    for (int c = 0; c < NCH; c++) s += pwp[c * 1024 + i];
    wts[(size_t)(b0 * 4 + bh) * 1024 + i] = s * rinvs[i & 31];
}

// ---- zero at2 borders: layout [bl][row][chgrp16][col PW][8] ----
__global__ __launch_bounds__(256) void k_bord(unsigned short* __restrict__ at2) {
    const int row = blockIdx.x, bl = blockIdx.y, tx = threadIdx.x;
    unsigned short* base = at2 + (size_t)(bl * PW + row) * 16 * PW * 8;
    const uint4 z = make_uint4(0u, 0u, 0u, 0u);
    if (row == 0 || row == PW - 1) {
        for (int i = tx; i < 16 * PW; i += 256) ((uint4*)base)[i] = z;
    } else if (tx < 32) {
        int g = tx >> 1, c = (tx & 1) * (PW - 1);
        *(uint4*)(base + ((size_t)g * PW + c) * 8) = z;
    }
}

// ---- attnout via MFMA: D[px,e] = sum_d v[px,d] * W[d,e]; writes at2 subtiled NHWC ----
// grid (NPIX/256, nb); wave handles 64 px (2 tiles of 32)
__global__ __launch_bounds__(256, 4) void k_attnout(
    const unsigned short* __restrict__ vt, const float* __restrict__ wts,
    unsigned short* __restrict__ at2, int b0, int nb)
{
    const int bl = blockIdx.y, b = b0 + bl;
    const int tx = threadIdx.x, wv = tx >> 6, l = tx & 63;
    const int e = l & 31, kg = l >> 5;
    const int pxb = blockIdx.x * 256 + wv * 64;

    __shared__ float osa[4][32][34];

    // B-frags (W^T) in registers: Bf[h][kk], k = kk*16 + kg*8 + j
    short8 Bf[4][2];
    const float* Wb = wts + (size_t)b * 4096;
#pragma unroll
    for (int h = 0; h < 4; h++)
#pragma unroll
        for (int kk = 0; kk < 2; kk++) {
            short8 v;
#pragma unroll
            for (int j = 0; j < 8; j++) {
                int d = kk * 16 + kg * 8 + j;
                v[j] = (short)f2u(Wb[h * 1024 + d * 32 + e]);
            }
            Bf[h][kk] = v;
        }

    const unsigned short* vbase = vt + (size_t)bl * 2 * NPIX * 64;

#pragma unroll
    for (int t = 0; t < 2; t++) {
        const int px0 = pxb + t * 32;
#pragma unroll
        for (int h = 0; h < 4; h++) {
            const unsigned short* vp = vbase + (size_t)(h >> 1) * NPIX * 64
                                     + (size_t)(px0 + e) * 64 + (h & 1) * 32 + kg * 8;
            short8 a0 = *(const short8*)vp;
            short8 a1 = *(const short8*)(vp + 16);
            f32x16 acc;
#pragma unroll
            for (int r = 0; r < 16; r++) acc[r] = 0.f;
            acc = __builtin_amdgcn_mfma_f32_32x32x16_bf16(a0, Bf[h][0], acc, 0, 0, 0);
            acc = __builtin_amdgcn_mfma_f32_32x32x16_bf16(a1, Bf[h][1], acc, 0, 0, 0);

            // stage D: lane holds D[pxl][e], pxl = (r&3)+8*(r>>2)+4*kg
#pragma unroll
            for (int r = 0; r < 16; r++) {
                int pxl = (r & 3) + 8 * (r >> 2) + 4 * kg;
                osa[wv][e][pxl] = acc[r];
            }
            // store: 2 iters x (eg,px) units -> 16B contiguous, 512B runs
#pragma unroll
            for (int it = 0; it < 2; it++) {
                int u = it * 64 + l;
                int eg = u >> 5, px = u & 31;
                short8 o;
#pragma unroll
                for (int j = 0; j < 8; j++) o[j] = (short)f2u(osa[wv][eg * 8 + j][px]);
                int gp = px0 + px;
                int prow = gp >> 8, pcol = gp & 255;
                *(short8*)(at2 + (((size_t)(bl * PW) + 1 + prow) * 16 + h * 4 + eg) * (PW * 8)
                           + (size_t)(1 + pcol) * 8) = o;
            }
        }
    }
}

// ---- conv2: implicit GEMM from subtiled at2 ----
__global__ __launch_bounds__(256, 3) void k_conv2(
    const unsigned short* __restrict__ at2, const short* __restrict__ w2t,
    const float* __restrict__ b2, float* __restrict__ out, int b0, int nb)
{
    const int bid = blockIdx.x;
    const int chunk = bid & 1;
    const int y   = (bid >> 1) & 255;
    const int bl  = bid >> 9;
    const int px0 = chunk * 128;
    const int bb  = b0 + bl;
    const int tx  = threadIdx.x;
    const int wv  = tx >> 6, l = tx & 63;
    const int lhi = l >> 4, llo = l & 15;

    __shared__ short xs[12 * 132 * 8];
    __shared__ float osf[32][132];

    float bias[2][4];
#pragma unroll
    for (int m = 0; m < 2; m++)
#pragma unroll
        for (int r = 0; r < 4; r++)
            bias[m][r] = b2[m * 16 + lhi * 4 + r];

    f32x4 acc[2][2];
#pragma unroll
    for (int t = 0; t < 2; t++)
#pragma unroll
        for (int m = 0; m < 2; m++) acc[t][m] = (f32x4){0.f, 0.f, 0.f, 0.f};

    for (int cc = 0; cc < 4; cc++) {
        __syncthreads();
#pragma unroll
        for (int i = 0; i < 3; i++) {
            int p = wv * 3 + i;
            int r = p >> 2, ch = p & 3;
            const char* src = (const char*)at2 +
                (((size_t)(bl * PW) + y + r) * 16 + cc * 4 + ch) * (PW * 16)
                + (size_t)px0 * 16 + (size_t)l * 16;
            char* dst = (char*)xs + p * 2112;
            gload16(src, dst);
            gload16(src + 1024, dst + 1024);
            if (l < 2) gload16(src + 2048, dst + 2048);
        }
        __syncthreads();

        short8 a[2], an[2];
#pragma unroll
        for (int m = 0; m < 2; m++)
            an[m] = *(const short8*)(w2t + ((size_t)(cc * 4 + lhi) * 32 + m * 16 + llo) * 8);
#pragma unroll
        for (int tap = 0; tap < 9; tap++) {
            const int dy = tap / 3, dx = tap % 3;
#pragma unroll
            for (int m = 0; m < 2; m++) a[m] = an[m];
            if (tap < 8) {
#pragma unroll
                for (int m = 0; m < 2; m++)
                    an[m] = *(const short8*)(w2t +
                        ((size_t)((tap + 1) * 16 + cc * 4 + lhi) * 32 + m * 16 + llo) * 8);
            }
#pragma unroll
            for (int t = 0; t < 2; t++) {
                short8 bfr = *(const short8*)&xs[(((dy * 4 + lhi) * 132) + (wv * 32 + t * 16 + llo + dx)) * 8];
#pragma unroll
                for (int m = 0; m < 2; m++)
                    acc[t][m] = __builtin_amdgcn_mfma_f32_16x16x32_bf16(a[m], bfr, acc[t][m], 0, 0, 0);
            }
        }
    }

#pragma unroll
    for (int t = 0; t < 2; t++)
#pragma unroll
        for (int m = 0; m < 2; m++)
#pragma unroll
            for (int r = 0; r < 4; r++)
                osf[m * 16 + lhi * 4 + r][wv * 32 + t * 16 + llo] = acc[t][m][r] + bias[m][r];
    __syncthreads();
#pragma unroll
    for (int p = 0; p < 4; p++) {
        int chl = p * 8 + (tx >> 5);
        float4 v = *(const float4*)&osf[chl][(tx & 31) * 4];
        *(float4*)(out + ((size_t)bb * COUT + chl) * NPIX + y * WW + px0 + (tx & 31) * 4) = v;
    }
}

extern "C" void kernel_launch(void* const* d_in, const int* in_sizes, int n_in,
                              void* d_out, int out_size, void* d_ws, size_t ws_size,
                              hipStream_t stream) {
    const float* x  = (const float*)d_in[0];
    const float* w1 = (const float*)d_in[1];
    const float* b1 = (const float*)d_in[2];
    const float* w2 = (const float*)d_in[3];
    const float* b2 = (const float*)d_in[4];
    float* out = (float*)d_out;

    char* ws = (char*)d_ws;
    float* wts  = (float*)(ws + 4096);
    short* w1t  = (short*)(ws + 69632);
    short* w2t  = (short*)(ws + 290816);
    const size_t OFF_XT = 1048576;

    int nb = 4;
    {
        size_t xt_sz = (size_t)nb * PW * 4 * PW * 16;                 // xt2
        size_t total = OFF_XT + xt_sz + (size_t)2 * nb * CMID * NPIX * 2   // q,k
                     + (size_t)nb * 2 * NPIX * 64 * 2;                // vt
        if (ws_size < total) nb = 1;
    }
    const size_t xt_sz   = (size_t)nb * PW * 4 * PW * 16;
    const size_t qkv_off = OFF_XT + xt_sz;
    const size_t vt_off  = qkv_off + (size_t)2 * nb * CMID * NPIX * 2;

    unsigned short* xt2 = (unsigned short*)(ws + OFF_XT);
    unsigned short* qkv = (unsigned short*)(ws + qkv_off);
    unsigned short* vt  = (unsigned short*)(ws + vt_off);
    unsigned short* at2 = (unsigned short*)(ws + qkv_off);  // overlays q+k (dead after k_weights)
    float* pw = (float*)(ws + OFF_XT);                      // overlays xt2 (dead after conv1)
    float* ps = (float*)(ws + OFF_XT + (size_t)nb * 4 * NCH * 1024 * 4);

    k_w1t<<<dim3(9), 256, 0, stream>>>(w1, w1t);
    k_w2t<<<dim3(9), 256, 0, stream>>>(w2, w2t);

    for (int b0 = 0; b0 < B_; b0 += nb) {
        k_xt2    <<<dim3(PW, nb),        256, 0, stream>>>(x, xt2, b0);
        k_conv1  <<<dim3(2 * HH * nb),   256, 0, stream>>>(xt2, w1t, b1, qkv, vt, nb);
        k_weights<<<dim3(NCH, nb * 4),   256, 0, stream>>>(qkv, pw, ps, nb);
        k_wred   <<<dim3(nb * 4, 4),     256, 0, stream>>>(pw, ps, wts, b0);
        k_bord   <<<dim3(PW, nb),        256, 0, stream>>>(at2);
        k_attnout<<<dim3(NPIX / 256, nb),256, 0, stream>>>(vt, wts, at2, b0, nb);
        k_conv2  <<<dim3(2 * HH * nb),   256, 0, stream>>>(at2, w2t, b2, out, b0, nb);
    }
}

// Round 10
// 231.737 us; speedup vs baseline: 14.2191x; 1.0201x over previous
//
#include <hip/hip_runtime.h>
#include <hip/hip_bf16.h>

typedef __hip_bfloat16 bf16;
typedef __attribute__((ext_vector_type(8))) short short8;
typedef __attribute__((ext_vector_type(4))) float f32x4;
typedef __attribute__((ext_vector_type(16))) float f32x16;

#define B_    4
#define CIN   32
#define HH    256
#define WW    256
#define C1    384
#define NPIX  65536
#define CMID  128
#define COUT  32
#define PW    258
#define NCH   64

static __device__ __forceinline__ float u2f(unsigned short u) {
    unsigned int x = ((unsigned int)u) << 16;
    return __uint_as_float(x);
}
static __device__ __forceinline__ unsigned short f2u(float f) {
    bf16 h = __float2bfloat16(f);
    return __builtin_bit_cast(unsigned short, h);
}
static __device__ __forceinline__ unsigned int pk2(float lo, float hi) {
    return (unsigned int)f2u(lo) | ((unsigned int)f2u(hi) << 16);
}
static __device__ __forceinline__ void gload16(const void* src, void* dst) {
    __builtin_amdgcn_global_load_lds(
        (const __attribute__((address_space(1))) void*)src,
        (__attribute__((address_space(3))) void*)dst, 16, 0, 0);
}

// ---- w1(384,32,3,3) fp32 -> w1t[tap][cihi4][co384][8] bf16 ----
__global__ __launch_bounds__(256) void k_w1t(const float* __restrict__ w1, short* __restrict__ w1t) {
    const int tap = blockIdx.x;
    for (int i = threadIdx.x; i < 384 * 32; i += 256) {
        int co = i >> 5, cij = i & 31;
        w1t[((size_t)(tap * 4 + (cij >> 3)) * 384 + co) * 8 + (cij & 7)] =
            (short)f2u(w1[(size_t)i * 9 + tap]);
    }
}
// ---- w2(32,128,3,3) fp32 -> w2t[tap][cihi16][co32][8] bf16 ----
__global__ __launch_bounds__(256) void k_w2t(const float* __restrict__ w2, short* __restrict__ w2t) {
    const int tap = blockIdx.x;
    for (int i = threadIdx.x; i < 32 * 128; i += 256) {
        int co = i >> 7, cij = i & 127;
        w2t[((size_t)(tap * 16 + (cij >> 3)) * 32 + co) * 8 + (cij & 7)] =
            (short)f2u(w2[(size_t)i * 9 + tap]);
    }
}

// ---- x -> xt2[bl][row][cihi4][col PW][8ch] bf16, zero-padded ----
__global__ __launch_bounds__(256) void k_xt2(const float* __restrict__ x,
                                             unsigned short* __restrict__ xt2, int b0) {
    const int row = blockIdx.x, bl = blockIdx.y, b = b0 + bl;
    const int tx = threadIdx.x;
    unsigned short* rbase = xt2 + (size_t)(bl * PW + row) * 4 * PW * 8;
    const uint4 z = make_uint4(0u, 0u, 0u, 0u);
    if (row == 0 || row == PW - 1) {
        for (int i = tx; i < 4 * PW; i += 256) ((uint4*)rbase)[i] = z;
        return;
    }
    if (tx < 2) {
        int c = tx ? (PW - 1) : 0;
#pragma unroll
        for (int ch = 0; ch < 4; ch++)
            *(uint4*)(rbase + ((size_t)ch * PW + c) * 8) = z;
    }
    const int col = tx + 1;
    const size_t px = (size_t)(row - 1) * WW + tx;
    unsigned int pk[16];
#pragma unroll
    for (int c2 = 0; c2 < 16; c2++) {
        float v0 = x[((size_t)b * CIN + 2 * c2) * NPIX + px];
        float v1 = x[((size_t)b * CIN + 2 * c2 + 1) * NPIX + px];
        pk[c2] = pk2(v0, v1);
    }
#pragma unroll
    for (int ch = 0; ch < 4; ch++)
        *(uint4*)(rbase + ((size_t)ch * PW + col) * 8) =
            make_uint4(pk[ch * 4], pk[ch * 4 + 1], pk[ch * 4 + 2], pk[ch * 4 + 3]);
}

// ---- conv1: merged-co implicit GEMM; raw barriers + counted vmcnt (stores stay in flight) ----
__global__ __launch_bounds__(256, 2) void k_conv1(
    const unsigned short* __restrict__ xt2, const short* __restrict__ w1t,
    const float* __restrict__ b1, unsigned short* __restrict__ qkv,
    unsigned short* __restrict__ vt, int nb)
{
    const int bid = blockIdx.x;
    const int chunk = bid & 1;
    const int y   = (bid >> 1) & 255;
    const int bl  = bid >> 9;
    const int px0 = chunk * 128;
    const int tx  = threadIdx.x;
    const int wv  = tx >> 6, l = tx & 63;
    const int lhi = l >> 4, llo = l & 15;

    __shared__ short xs[12 * 132 * 8];      // 25344 B
    __shared__ short wt[9][4][64][8];       // 36864 B
    __shared__ union { short os[64][136]; short ost[128][66]; } ou;  // 17408 B
    __shared__ float bs[384];               // 1536 B   (total 81152 B -> 2 blocks/CU)

    for (int i = tx; i < 384; i += 256) bs[i] = b1[i];

    // stage x patch: 12 (row,cihi) segs of 130 cols
#pragma unroll
    for (int i = 0; i < 3; i++) {
        int p = wv * 3 + i;
        int r = p >> 2, ch = p & 3;
        const char* src = (const char*)xt2 +
            (((size_t)(bl * PW) + y + r) * 4 + ch) * (PW * 16) + (size_t)px0 * 16 + (size_t)l * 16;
        char* dst = (char*)xs + p * 2112;
        gload16(src, dst);
        gload16(src + 1024, dst + 1024);
        if (l < 2) gload16(src + 2048, dst + 2048);
    }
    // stage weight tile cog0
#pragma unroll
    for (int i = 0; i < 9; i++) {
        int s = wv * 9 + i;
        int tap = s >> 2, ch = s & 3;
        const char* src = (const char*)w1t + ((size_t)(tap * 4 + ch) * 384) * 16 + (size_t)l * 16;
        gload16(src, (char*)&wt[tap][ch][0][0]);
    }
    __syncthreads();

#pragma unroll
    for (int cog = 0; cog < 6; cog++) {
        if (cog > 0) {
            // wait prefetched wt tile landed (9 gloads older than the 4 in-flight stores)
            asm volatile("s_waitcnt vmcnt(4)" ::: "memory");
            __builtin_amdgcn_s_barrier();
            __builtin_amdgcn_sched_barrier(0);
        }
        const int co0 = cog * 64;

        f32x4 acc[2][4];
#pragma unroll
        for (int t = 0; t < 2; t++)
#pragma unroll
            for (int mc = 0; mc < 4; mc++) acc[t][mc] = (f32x4){0.f, 0.f, 0.f, 0.f};

#pragma unroll
        for (int tap = 0; tap < 9; tap++) {
            const int dy = tap / 3, dx = tap % 3;
            short8 a[4];
#pragma unroll
            for (int mc = 0; mc < 4; mc++)
                a[mc] = *(const short8*)&wt[tap][lhi][mc * 16 + llo][0];
#pragma unroll
            for (int t = 0; t < 2; t++) {
                short8 bfr = *(const short8*)&xs[(((dy * 4 + lhi) * 132) + (wv * 32 + t * 16 + llo + dx)) * 8];
#pragma unroll
                for (int mc = 0; mc < 4; mc++)
                    acc[t][mc] = __builtin_amdgcn_mfma_f32_16x16x32_bf16(a[mc], bfr, acc[t][mc], 0, 0, 0);
            }
        }

        // bias from LDS (no vmcnt ops in loop), stage output tile
        float bias[4][4];
#pragma unroll
        for (int mc = 0; mc < 4; mc++)
#pragma unroll
            for (int r = 0; r < 4; r++)
                bias[mc][r] = bs[co0 + mc * 16 + lhi * 4 + r];

        if (cog < 4) {     // q,k: channel-major staging
#pragma unroll
            for (int t = 0; t < 2; t++)
#pragma unroll
                for (int mc = 0; mc < 4; mc++)
#pragma unroll
                    for (int r = 0; r < 4; r++)
                        ou.os[mc * 16 + lhi * 4 + r][wv * 32 + t * 16 + llo] =
                            (short)f2u(acc[t][mc][r] + bias[mc][r]);
        } else {           // v: transposed [px][ch] staging
#pragma unroll
            for (int t = 0; t < 2; t++)
#pragma unroll
                for (int mc = 0; mc < 4; mc++)
#pragma unroll
                    for (int r = 0; r < 4; r++)
                        ou.ost[wv * 32 + t * 16 + llo][mc * 16 + lhi * 4 + r] =
                            (short)f2u(acc[t][mc][r] + bias[mc][r]);
        }

        // all wt reads done (each wave's ds_reads complete before its MFMA consumed them)
        // + os writes visible after this barrier
        asm volatile("s_waitcnt lgkmcnt(0)" ::: "memory");
        __builtin_amdgcn_s_barrier();
        __builtin_amdgcn_sched_barrier(0);

        // prefetch next weight tile (issued BEFORE this cog's stores -> vmcnt(4) at next top)
        if (cog < 5) {
#pragma unroll
            for (int i = 0; i < 9; i++) {
                int s = wv * 9 + i;
                int tap = s >> 2, ch = s & 3;
                const char* src = (const char*)w1t +
                    ((size_t)(tap * 4 + ch) * 384 + co0 + 64) * 16 + (size_t)l * 16;
                gload16(src, (char*)&wt[tap][ch][0][0]);
            }
        }

        if (cog < 4) {
#pragma unroll
            for (int p = 0; p < 4; p++) {
                int chl = p * 16 + (tx >> 4);
                int c = co0 + chl;
                int comp = c >> 7, chn = c & 127;
                uint4 v = *(const uint4*)&ou.os[chl][(tx & 15) * 8];
                *(uint4*)(qkv + ((size_t)(comp * nb + bl) * CMID + chn) * NPIX
                          + y * WW + px0 + (tx & 15) * 8) = v;
            }
        } else {
            const int px = tx >> 1, half = tx & 1;
            const uint4* ls = (const uint4*)&ou.ost[px][half * 32];
            uint4 v0 = ls[0], v1 = ls[1], v2 = ls[2], v3 = ls[3];
            unsigned short* dst = vt + ((size_t)(bl * 2 + (cog - 4)) * NPIX
                                        + y * WW + px0 + px) * 64 + half * 32;
            ((uint4*)dst)[0] = v0; ((uint4*)dst)[1] = v1;
            ((uint4*)dst)[2] = v2; ((uint4*)dst)[3] = v3;
        }
    }
}

// ---- weights GEMM partials ----
__global__ __launch_bounds__(256) void k_weights(
    const unsigned short* __restrict__ qkv, float* __restrict__ pw,
    float* __restrict__ ps, int nb)
{
    const int c  = blockIdx.x;
    const int bh = blockIdx.y;
    const int bl = bh >> 2, h = bh & 3;
    const int tx = threadIdx.x;
    const int wv = tx >> 6, l = tx & 63;
    const int col = l & 31;
    const int kg  = l >> 5;

    const unsigned short* qb = qkv + ((size_t)bl * CMID + h * 32 + col) * NPIX;
    const unsigned short* kb = qkv + ((size_t)(nb + bl) * CMID + h * 32 + col) * NPIX;
    const int n0 = c * 1024 + wv * 256 + kg * 8;

    f32x16 acc;
#pragma unroll
    for (int r = 0; r < 16; r++) acc[r] = 0.f;
    float se = 0.f;

#pragma unroll 4
    for (int s = 0; s < 16; s++) {
        const int n = n0 + s * 16;
        short8 qf = *(const short8*)(qb + n);
        short8 kf = *(const short8*)(kb + n);
        float ef[8];
#pragma unroll
        for (int j = 0; j < 8; j++) {
            ef[j] = __expf(u2f((unsigned short)kf[j]));
            se += ef[j];
        }
        short8 pf;
#pragma unroll
        for (int j = 0; j < 8; j++) pf[j] = (short)f2u(ef[j]);
        acc = __builtin_amdgcn_mfma_f32_32x32x16_bf16(qf, pf, acc, 0, 0, 0);
    }

    __shared__ float red[4][1024];
    __shared__ float sred[4][64];
#pragma unroll
    for (int r = 0; r < 16; r++) {
        int row = (r & 3) + 8 * (r >> 2) + 4 * kg;
        red[wv][row * 32 + col] = acc[r];
    }
    sred[wv][l] = se;
    __syncthreads();

    float* pwp = pw + ((size_t)bh * NCH + c) * 1024;
#pragma unroll
    for (int j = 0; j < 4; j++) {
        int i = tx + 256 * j;
        pwp[i] = red[0][i] + red[1][i] + red[2][i] + red[3][i];
    }
    if (tx < 32) {
        float s = 0.f;
#pragma unroll
        for (int w = 0; w < 4; w++) s += sred[w][tx] + sred[w][tx + 32];
        ps[((size_t)bh * NCH + c) * 32 + tx] = s;
    }
}

// ---- reduce partials ----
__global__ __launch_bounds__(256) void k_wred(
    const float* __restrict__ pw, const float* __restrict__ ps,
    float* __restrict__ wts, int b0)
{
    const int bh = blockIdx.x;
    const int jq = blockIdx.y;
    const int tx = threadIdx.x;
    __shared__ float rinvs[32];
    if (tx < 32) {
        float s = 0.f;
        for (int c = 0; c < NCH; c++) s += ps[((size_t)bh * NCH + c) * 32 + tx];
        rinvs[tx] = 1.f / s;
    }
    __syncthreads();
    const int i = jq * 256 + tx;
    const float* pwp = pw + (size_t)bh * NCH * 1024;
    float s = 0.f;
    for (int c = 0; c < NCH; c++) s += pwp[c * 1024 + i];
    wts[(size_t)(b0 * 4 + bh) * 1024 + i] = s * rinvs[i & 31];
}

// ---- zero at2 borders: layout [bl][row][chgrp16][col PW][8] ----
__global__ __launch_bounds__(256) void k_bord(unsigned short* __restrict__ at2) {
    const int row = blockIdx.x, bl = blockIdx.y, tx = threadIdx.x;
    unsigned short* base = at2 + (size_t)(bl * PW + row) * 16 * PW * 8;
    const uint4 z = make_uint4(0u, 0u, 0u, 0u);
    if (row == 0 || row == PW - 1) {
        for (int i = tx; i < 16 * PW; i += 256) ((uint4*)base)[i] = z;
    } else if (tx < 32) {
        int g = tx >> 1, c = (tx & 1) * (PW - 1);
        *(uint4*)(base + ((size_t)g * PW + c) * 8) = z;
    }
}

// ---- attnout via MFMA ----
__global__ __launch_bounds__(256, 4) void k_attnout(
    const unsigned short* __restrict__ vt, const float* __restrict__ wts,
    unsigned short* __restrict__ at2, int b0, int nb)
{
    const int bl = blockIdx.y, b = b0 + bl;
    const int tx = threadIdx.x, wv = tx >> 6, l = tx & 63;
    const int e = l & 31, kg = l >> 5;
    const int pxb = blockIdx.x * 256 + wv * 64;

    __shared__ float osa[4][32][34];

    short8 Bf[4][2];
    const float* Wb = wts + (size_t)b * 4096;
#pragma unroll
    for (int h = 0; h < 4; h++)
#pragma unroll
        for (int kk = 0; kk < 2; kk++) {
            short8 v;
#pragma unroll
            for (int j = 0; j < 8; j++) {
                int d = kk * 16 + kg * 8 + j;
                v[j] = (short)f2u(Wb[h * 1024 + d * 32 + e]);
            }
            Bf[h][kk] = v;
        }

    const unsigned short* vbase = vt + (size_t)bl * 2 * NPIX * 64;

#pragma unroll
    for (int t = 0; t < 2; t++) {
        const int px0 = pxb + t * 32;
#pragma unroll
        for (int h = 0; h < 4; h++) {
            const unsigned short* vp = vbase + (size_t)(h >> 1) * NPIX * 64
                                     + (size_t)(px0 + e) * 64 + (h & 1) * 32 + kg * 8;
            short8 a0 = *(const short8*)vp;
            short8 a1 = *(const short8*)(vp + 16);
            f32x16 acc;
#pragma unroll
            for (int r = 0; r < 16; r++) acc[r] = 0.f;
            acc = __builtin_amdgcn_mfma_f32_32x32x16_bf16(a0, Bf[h][0], acc, 0, 0, 0);
            acc = __builtin_amdgcn_mfma_f32_32x32x16_bf16(a1, Bf[h][1], acc, 0, 0, 0);

#pragma unroll
            for (int r = 0; r < 16; r++) {
                int pxl = (r & 3) + 8 * (r >> 2) + 4 * kg;
                osa[wv][e][pxl] = acc[r];
            }
#pragma unroll
            for (int it = 0; it < 2; it++) {
                int u = it * 64 + l;
                int eg = u >> 5, px = u & 31;
                short8 o;
#pragma unroll
                for (int j = 0; j < 8; j++) o[j] = (short)f2u(osa[wv][eg * 8 + j][px]);
                int gp = px0 + px;
                int prow = gp >> 8, pcol = gp & 255;
                *(short8*)(at2 + (((size_t)(bl * PW) + 1 + prow) * 16 + h * 4 + eg) * (PW * 8)
                           + (size_t)(1 + pcol) * 8) = o;
            }
        }
    }
}

// ---- conv2: implicit GEMM from subtiled at2 ----
__global__ __launch_bounds__(256, 3) void k_conv2(
    const unsigned short* __restrict__ at2, const short* __restrict__ w2t,
    const float* __restrict__ b2, float* __restrict__ out, int b0, int nb)
{
    const int bid = blockIdx.x;
    const int chunk = bid & 1;
    const int y   = (bid >> 1) & 255;
    const int bl  = bid >> 9;
    const int px0 = chunk * 128;
    const int bb  = b0 + bl;
    const int tx  = threadIdx.x;
    const int wv  = tx >> 6, l = tx & 63;
    const int lhi = l >> 4, llo = l & 15;

    __shared__ short xs[12 * 132 * 8];
    __shared__ float osf[32][132];

    float bias[2][4];
#pragma unroll
    for (int m = 0; m < 2; m++)
#pragma unroll
        for (int r = 0; r < 4; r++)
            bias[m][r] = b2[m * 16 + lhi * 4 + r];

    f32x4 acc[2][2];
#pragma unroll
    for (int t = 0; t < 2; t++)
#pragma unroll
        for (int m = 0; m < 2; m++) acc[t][m] = (f32x4){0.f, 0.f, 0.f, 0.f};

    for (int cc = 0; cc < 4; cc++) {
        __syncthreads();
#pragma unroll
        for (int i = 0; i < 3; i++) {
            int p = wv * 3 + i;
            int r = p >> 2, ch = p & 3;
            const char* src = (const char*)at2 +
                (((size_t)(bl * PW) + y + r) * 16 + cc * 4 + ch) * (PW * 16)
                + (size_t)px0 * 16 + (size_t)l * 16;
            char* dst = (char*)xs + p * 2112;
            gload16(src, dst);
            gload16(src + 1024, dst + 1024);
            if (l < 2) gload16(src + 2048, dst + 2048);
        }
        __syncthreads();

        short8 a[2], an[2];
#pragma unroll
        for (int m = 0; m < 2; m++)
            an[m] = *(const short8*)(w2t + ((size_t)(cc * 4 + lhi) * 32 + m * 16 + llo) * 8);
#pragma unroll
        for (int tap = 0; tap < 9; tap++) {
            const int dy = tap / 3, dx = tap % 3;
#pragma unroll
            for (int m = 0; m < 2; m++) a[m] = an[m];
            if (tap < 8) {
#pragma unroll
                for (int m = 0; m < 2; m++)
                    an[m] = *(const short8*)(w2t +
                        ((size_t)((tap + 1) * 16 + cc * 4 + lhi) * 32 + m * 16 + llo) * 8);
            }
#pragma unroll
            for (int t = 0; t < 2; t++) {
                short8 bfr = *(const short8*)&xs[(((dy * 4 + lhi) * 132) + (wv * 32 + t * 16 + llo + dx)) * 8];
#pragma unroll
                for (int m = 0; m < 2; m++)
                    acc[t][m] = __builtin_amdgcn_mfma_f32_16x16x32_bf16(a[m], bfr, acc[t][m], 0, 0, 0);
            }
        }
    }

#pragma unroll
    for (int t = 0; t < 2; t++)
#pragma unroll
        for (int m = 0; m < 2; m++)
#pragma unroll
            for (int r = 0; r < 4; r++)
                osf[m * 16 + lhi * 4 + r][wv * 32 + t * 16 + llo] = acc[t][m][r] + bias[m][r];
    __syncthreads();
#pragma unroll
    for (int p = 0; p < 4; p++) {
        int chl = p * 8 + (tx >> 5);
        float4 v = *(const float4*)&osf[chl][(tx & 31) * 4];
        *(float4*)(out + ((size_t)bb * COUT + chl) * NPIX + y * WW + px0 + (tx & 31) * 4) = v;
    }
}

extern "C" void kernel_launch(void* const* d_in, const int* in_sizes, int n_in,
                              void* d_out, int out_size, void* d_ws, size_t ws_size,
                              hipStream_t stream) {
    const float* x  = (const float*)d_in[0];
    const float* w1 = (const float*)d_in[1];
    const float* b1 = (const float*)d_in[2];
    const float* w2 = (const float*)d_in[3];
    const float* b2 = (const float*)d_in[4];
    float* out = (float*)d_out;

    char* ws = (char*)d_ws;
    float* wts  = (float*)(ws + 4096);
    short* w1t  = (short*)(ws + 69632);
    short* w2t  = (short*)(ws + 290816);
    const size_t OFF_XT = 1048576;

    int nb = 4;
    {
        size_t xt_sz = (size_t)nb * PW * 4 * PW * 16;
        size_t total = OFF_XT + xt_sz + (size_t)2 * nb * CMID * NPIX * 2
                     + (size_t)nb * 2 * NPIX * 64 * 2;
        if (ws_size < total) nb = 1;
    }
    const size_t xt_sz   = (size_t)nb * PW * 4 * PW * 16;
    const size_t qkv_off = OFF_XT + xt_sz;
    const size_t vt_off  = qkv_off + (size_t)2 * nb * CMID * NPIX * 2;

    unsigned short* xt2 = (unsigned short*)(ws + OFF_XT);
    unsigned short* qkv = (unsigned short*)(ws + qkv_off);
    unsigned short* vt  = (unsigned short*)(ws + vt_off);
    unsigned short* at2 = (unsigned short*)(ws + qkv_off);
    float* pw = (float*)(ws + OFF_XT);
    float* ps = (float*)(ws + OFF_XT + (size_t)nb * 4 * NCH * 1024 * 4);

    k_w1t<<<dim3(9), 256, 0, stream>>>(w1, w1t);
    k_w2t<<<dim3(9), 256, 0, stream>>>(w2, w2t);

    for (int b0 = 0; b0 < B_; b0 += nb) {
        k_xt2    <<<dim3(PW, nb),        256, 0, stream>>>(x, xt2, b0);
        k_conv1  <<<dim3(2 * HH * nb),   256, 0, stream>>>(xt2, w1t, b1, qkv, vt, nb);
        k_weights<<<dim3(NCH, nb * 4),   256, 0, stream>>>(qkv, pw, ps, nb);
        k_wred   <<<dim3(nb * 4, 4),     256, 0, stream>>>(pw, ps, wts, b0);
        k_bord   <<<dim3(PW, nb),        256, 0, stream>>>(at2);
        k_attnout<<<dim3(NPIX / 256, nb),256, 0, stream>>>(vt, wts, at2, b0, nb);
        k_conv2  <<<dim3(2 * HH * nb),   256, 0, stream>>>(at2, w2t, b2, out, b0, nb);
    }
}